// Round 2
// baseline (59149.316 us; speedup 1.0000x reference)
//
#include <hip/hip_runtime.h>

typedef _Float16 f16;
typedef _Float16 h2 __attribute__((ext_vector_type(2)));

#define BB    64
#define UU    256
#define HH    128
#define MELM  80
#define RRR   5
#define G3    768

// ---- h2-unit offsets: pair-interleaved fp16 weights, layout [K/2][N] of h2 ----
constexpr unsigned O_WP1T  = 0;        // N=256 K=80   (10240)
constexpr unsigned O_WP2T  = 10240;    // N=128 K=256  (16384)
constexpr unsigned O_WAIH  = 26624;    // N=768 K=128  (49152)
constexpr unsigned O_WAHH  = 75776;    // N=768 K=256  (98304)
constexpr unsigned O_W2T   = 174080;   // N=256 K=256  (32768)
constexpr unsigned O_WPROJ = 206848;   // N=256 K=512  (65536)
constexpr unsigned O_W1IH  = 272384;   // N=768 K=256
constexpr unsigned O_W1HH  = 370688;
constexpr unsigned O_W2IH  = 468992;
constexpr unsigned O_W2HH  = 567296;
constexpr unsigned O_WOUT  = 665600;   // N=400 K=256  (51200) -> end 716800 h2
// ---- half-unit offsets ----
constexpr size_t OH_KEYS = 1433600;    // 64*1000*256 halfs
constexpr size_t OH_MEM  = 17817600;   // 64*1000*256 halfs -> end 34201600
// ---- float-unit offset (fp32 W1^T for k_keys) ----
constexpr size_t OF_W1T  = 17100800;   // 256*256 floats

#if defined(__has_builtin)
#if __has_builtin(__builtin_amdgcn_fdot2)
#define USE_FDOT2 1
#endif
#endif

__device__ __forceinline__ float dot2f(h2 a, h2 b, float c){
#ifdef USE_FDOT2
  return __builtin_amdgcn_fdot2(a, b, c, false);
#else
  return c + (float)a[0]*(float)b[0] + (float)a[1]*(float)b[1];
#endif
}

__device__ __forceinline__ float fsig(float x){ return 1.0f/(1.0f+__expf(-x)); }
__device__ __forceinline__ float ftanh(float x){ return 1.0f - 2.0f/(1.0f+__expf(2.0f*x)); }

// acc[0..3] += sum_k act[k] * W[k][j4*4 .. +3]; W pair-interleaved [K/2][N] h2
template<int K, int NF4>
__device__ __forceinline__ void gemv4h(const h2* __restrict__ Wt, const h2* __restrict__ acth,
                                       int j4, float* acc){
  const float4* __restrict__ w = reinterpret_cast<const float4*>(Wt) + j4;
  #pragma unroll 8
  for (int k2 = 0; k2 < K/2; ++k2){
    float4 wp = w[(size_t)k2*NF4];
    h2 a = acth[k2];
    const h2* wh = reinterpret_cast<const h2*>(&wp);
    acc[0] = dot2f(wh[0], a, acc[0]);
    acc[1] = dot2f(wh[1], a, acc[1]);
    acc[2] = dot2f(wh[2], a, acc[2]);
    acc[3] = dot2f(wh[3], a, acc[3]);
  }
}

template<int K, int NF4>
__device__ __forceinline__ void gemv4h_f32a(const h2* __restrict__ Wt, const float* __restrict__ act,
                                            int j4, float* acc){
  const float4* __restrict__ w = reinterpret_cast<const float4*>(Wt) + j4;
  #pragma unroll 8
  for (int k2 = 0; k2 < K/2; ++k2){
    float4 wp = w[(size_t)k2*NF4];
    h2 a; a[0] = (f16)act[2*k2]; a[1] = (f16)act[2*k2+1];
    const h2* wh = reinterpret_cast<const h2*>(&wp);
    acc[0] = dot2f(wh[0], a, acc[0]);
    acc[1] = dot2f(wh[1], a, acc[1]);
    acc[2] = dot2f(wh[2], a, acc[2]);
    acc[3] = dot2f(wh[3], a, acc[3]);
  }
}

__device__ __forceinline__ void pack2(h2* dst, int j4, const float* a){
  h2 p0; p0[0]=(f16)a[0]; p0[1]=(f16)a[1];
  h2 p1; p1[0]=(f16)a[2]; p1[1]=(f16)a[3];
  dst[2*j4]   = p0;
  dst[2*j4+1] = p1;
}

// src [N][K] fp32 row-major -> dst pair-interleaved [K/2][N] h2
__global__ void k_tr_h(const float* __restrict__ src, h2* __restrict__ dst, int N, int K){
  int idx = blockIdx.x*blockDim.x + threadIdx.x;
  int tot = N*(K/2);
  if (idx < tot){
    int k2 = idx / N, n = idx - k2*N;
    h2 p; p[0] = (f16)src[n*K + 2*k2]; p[1] = (f16)src[n*K + 2*k2 + 1];
    dst[idx] = p;
  }
}

// fp32 transpose (for W1^T used by k_keys)
__global__ void k_transpose(const float* __restrict__ src, float* __restrict__ dst, int N, int K){
  int idx = blockIdx.x*blockDim.x + threadIdx.x;
  if (idx < N*K){
    int n = idx / K, k = idx - n*K;
    dst[k*N + n] = src[idx];
  }
}

__global__ void k_memh(const float* __restrict__ src, f16* __restrict__ dst, int n8){
  int i = blockIdx.x*blockDim.x + threadIdx.x;
  if (i < n8){
    const float4* s = reinterpret_cast<const float4*>(src) + 2*(size_t)i;
    float4 f0 = s[0], f1 = s[1];
    union { f16 h[8]; float4 v; } u;
    u.h[0]=(f16)f0.x; u.h[1]=(f16)f0.y; u.h[2]=(f16)f0.z; u.h[3]=(f16)f0.w;
    u.h[4]=(f16)f1.x; u.h[5]=(f16)f1.y; u.h[6]=(f16)f1.z; u.h[7]=(f16)f1.w;
    reinterpret_cast<float4*>(dst)[i] = u.v;
  }
}

// keys[b][t][c] = sum_u mem[b][t][u]*W1[c][u]; W1t fp32 [u][c]; output fp16
__global__ __launch_bounds__(256) void k_keys(const float* __restrict__ mem,
      const float* __restrict__ W1t, f16* __restrict__ keys, int T)
{
  const int b = blockIdx.z;
  const int tbase = blockIdx.x * 128;
  const int cbase = blockIdx.y * 128;
  const int tid = threadIdx.x;
  const int rt = tid >> 4, ct = tid & 15;
  const float* memb = mem + (size_t)b*T*UU;

  float acc[8][8];
  #pragma unroll
  for (int i=0;i<8;i++){
    #pragma unroll
    for (int j=0;j<8;j++) acc[i][j]=0.f;
  }
  const float* arow[8];
  #pragma unroll
  for (int i=0;i<8;i++){
    int t = tbase + rt*8 + i;
    arow[i] = memb + (size_t)(t < T ? t : T-1)*UU;
  }
  const float* wcol = W1t + cbase + ct*8;

  for (int k=0;k<UU;k+=4){
    float w8[4][8];
    #pragma unroll
    for (int kk=0;kk<4;kk++){
      float4 lo = *reinterpret_cast<const float4*>(wcol + (size_t)(k+kk)*UU);
      float4 hi = *reinterpret_cast<const float4*>(wcol + (size_t)(k+kk)*UU + 4);
      w8[kk][0]=lo.x; w8[kk][1]=lo.y; w8[kk][2]=lo.z; w8[kk][3]=lo.w;
      w8[kk][4]=hi.x; w8[kk][5]=hi.y; w8[kk][6]=hi.z; w8[kk][7]=hi.w;
    }
    #pragma unroll
    for (int i=0;i<8;i++){
      float4 a = *reinterpret_cast<const float4*>(arow[i] + k);
      float a4[4] = {a.x, a.y, a.z, a.w};
      #pragma unroll
      for (int kk=0;kk<4;kk++){
        #pragma unroll
        for (int j=0;j<8;j++) acc[i][j] += a4[kk]*w8[kk][j];
      }
    }
  }
  #pragma unroll
  for (int i=0;i<8;i++){
    int t = tbase + rt*8 + i;
    if (t < T){
      f16* dst = keys + (size_t)b*T*UU + (size_t)t*UU + cbase + ct*8;
      union { f16 h[8]; float4 v; } u;
      #pragma unroll
      for (int j=0;j<8;j++) u.h[j] = (f16)acc[i][j];
      *reinterpret_cast<float4*>(dst) = u.v;
    }
  }
}

// persistent decoder: 1 block/batch, 1024 threads, all steps in-loop
__global__ __launch_bounds__(1024) void k_decode(
    const h2* __restrict__ wts, const f16* __restrict__ keysg, const f16* __restrict__ memg,
    const float* __restrict__ bp1, const float* __restrict__ bp2,
    const float* __restrict__ vvec,
    const float* __restrict__ ba_ih, const float* __restrict__ ba_hh,
    const float* __restrict__ b1_ih, const float* __restrict__ b1_hh,
    const float* __restrict__ b2_ih, const float* __restrict__ b2_hh,
    const float* __restrict__ bproj, const float* __restrict__ bout,
    float* __restrict__ out, int T, int steps)
{
  __shared__ __align__(16) float s_prev[MELM];
  __shared__ __align__(16) h2    s_x1h[128];
  __shared__ __align__(16) h2    s_xh[64];
  __shared__ __align__(16) float s_ha[UU];
  __shared__ __align__(16) h2    s_hah[128];
  __shared__ __align__(16) float s_q[UU];
  __shared__ __align__(16) float s_gi[G3];
  __shared__ __align__(16) float s_gha[G3];
  __shared__ __align__(16) float s_gh1[G3];
  __shared__ __align__(16) float s_gh2[G3];
  __shared__ __align__(16) float s_g1h[UU];
  __shared__ __align__(16) h2    s_g1hh[128];
  __shared__ __align__(16) float s_g2h[UU];
  __shared__ __align__(16) h2    s_g2hh[128];
  __shared__ __align__(16) float s_g1in[UU];
  __shared__ __align__(16) h2    s_g1inh[128];
  __shared__ __align__(16) float s_g2in[UU];
  __shared__ __align__(16) h2    s_g2inh[128];
  __shared__ __align__(16) h2    s_s2h[128];
  __shared__ __align__(16) h2    s_ctxh[128];
  __shared__ __align__(16) float s_sc[1024];
  __shared__ __align__(16) float s_red[16*UU];
  __shared__ float s_wred[16];
  __shared__ float s_scal[2];

  const int b = blockIdx.x;
  const int tid = threadIdx.x;
  const int lane = tid & 63;
  const int wid = tid >> 6;
  const int half_id = lane >> 5;
  const int cl = lane & 31;

  const f16* keyb = keysg + (size_t)b*T*UU;
  const f16* memb = memg  + (size_t)b*T*UU;
  float* outb = out + (size_t)b*MELM*(steps*RRR);

  if (tid < 128){
    s_ha[2*tid]=0.f; s_ha[2*tid+1]=0.f;
    s_g1h[2*tid]=0.f; s_g1h[2*tid+1]=0.f;
    s_g2h[2*tid]=0.f; s_g2h[2*tid+1]=0.f;
    h2 z; z[0]=(f16)0.f; z[1]=(f16)0.f;
    s_hah[tid]=z; s_g1hh[tid]=z; s_g2hh[tid]=z;
  }
  if (tid < MELM) s_prev[tid] = 0.f;
  __syncthreads();

  float v8r[8];
  #pragma unroll
  for (int j=0;j<8;j++) v8r[j] = vvec[cl*8+j];

  for (int step = 0; step < steps; ++step){
    // ---- A: x1 = relu(Wp1 prev + bp1); gha/gh1/gh2 = W*_hh h + b*_hh
    if (tid < 64){
      float acc[4]={0.f,0.f,0.f,0.f};
      gemv4h_f32a<80,64>(wts + O_WP1T, s_prev, tid, acc);
      const float4 bbv = reinterpret_cast<const float4*>(bp1)[tid];
      acc[0]=fmaxf(acc[0]+bbv.x,0.f); acc[1]=fmaxf(acc[1]+bbv.y,0.f);
      acc[2]=fmaxf(acc[2]+bbv.z,0.f); acc[3]=fmaxf(acc[3]+bbv.w,0.f);
      pack2(s_x1h, tid, acc);
    } else if (tid < 256){
      int j4 = tid-64;
      float acc[4]={0.f,0.f,0.f,0.f};
      gemv4h<256,192>(wts + O_WAHH, s_hah, j4, acc);
      const float4 bbv = reinterpret_cast<const float4*>(ba_hh)[j4];
      float4 r; r.x=acc[0]+bbv.x; r.y=acc[1]+bbv.y; r.z=acc[2]+bbv.z; r.w=acc[3]+bbv.w;
      reinterpret_cast<float4*>(s_gha)[j4] = r;
    } else if (tid < 448){
      int j4 = tid-256;
      float acc[4]={0.f,0.f,0.f,0.f};
      gemv4h<256,192>(wts + O_W1HH, s_g1hh, j4, acc);
      const float4 bbv = reinterpret_cast<const float4*>(b1_hh)[j4];
      float4 r; r.x=acc[0]+bbv.x; r.y=acc[1]+bbv.y; r.z=acc[2]+bbv.z; r.w=acc[3]+bbv.w;
      reinterpret_cast<float4*>(s_gh1)[j4] = r;
    } else if (tid < 640){
      int j4 = tid-448;
      float acc[4]={0.f,0.f,0.f,0.f};
      gemv4h<256,192>(wts + O_W2HH, s_g2hh, j4, acc);
      const float4 bbv = reinterpret_cast<const float4*>(b2_hh)[j4];
      float4 r; r.x=acc[0]+bbv.x; r.y=acc[1]+bbv.y; r.z=acc[2]+bbv.z; r.w=acc[3]+bbv.w;
      reinterpret_cast<float4*>(s_gh2)[j4] = r;
    }
    __syncthreads();
    // ---- B: x = relu(Wp2 x1 + bp2)
    if (tid < 32){
      float acc[4]={0.f,0.f,0.f,0.f};
      gemv4h<256,32>(wts + O_WP2T, s_x1h, tid, acc);
      const float4 bbv = reinterpret_cast<const float4*>(bp2)[tid];
      acc[0]=fmaxf(acc[0]+bbv.x,0.f); acc[1]=fmaxf(acc[1]+bbv.y,0.f);
      acc[2]=fmaxf(acc[2]+bbv.z,0.f); acc[3]=fmaxf(acc[3]+bbv.w,0.f);
      pack2(s_xh, tid, acc);
    }
    __syncthreads();
    // ---- C: gi = Wa_ih x + ba_ih
    if (tid < 192){
      float acc[4]={0.f,0.f,0.f,0.f};
      gemv4h<128,192>(wts + O_WAIH, s_xh, tid, acc);
      const float4 bbv = reinterpret_cast<const float4*>(ba_ih)[tid];
      float4 r; r.x=acc[0]+bbv.x; r.y=acc[1]+bbv.y; r.z=acc[2]+bbv.z; r.w=acc[3]+bbv.w;
      reinterpret_cast<float4*>(s_gi)[tid] = r;
    }
    __syncthreads();
    // ---- D: attn GRU gates -> d_t (in s_ha / s_hah)
    if (tid < 128){
      float hn[2];
      #pragma unroll
      for (int d=0; d<2; ++d){
        int e = 2*tid + d;
        float r = fsig(s_gi[e] + s_gha[e]);
        float z = fsig(s_gi[256+e] + s_gha[256+e]);
        float n = ftanh(s_gi[512+e] + r*s_gha[512+e]);
        hn[d] = (1.f - z)*n + z*s_ha[e];
        s_ha[e] = hn[d];
      }
      h2 p; p[0]=(f16)hn[0]; p[1]=(f16)hn[1];
      s_hah[tid] = p;
    }
    __syncthreads();
    // ---- E: q = W2 d_t ; g1in = Wproj[:, :256] d_t + bproj
    if (tid < 64){
      float acc[4]={0.f,0.f,0.f,0.f};
      gemv4h<256,64>(wts + O_W2T, s_hah, tid, acc);
      float4 r; r.x=acc[0]; r.y=acc[1]; r.z=acc[2]; r.w=acc[3];
      reinterpret_cast<float4*>(s_q)[tid] = r;
    } else if (tid < 128){
      int j4 = tid-64;
      float acc[4]={0.f,0.f,0.f,0.f};
      gemv4h<256,64>(wts + O_WPROJ, s_hah, j4, acc);
      const float4 bbv = reinterpret_cast<const float4*>(bproj)[j4];
      float4 r; r.x=acc[0]+bbv.x; r.y=acc[1]+bbv.y; r.z=acc[2]+bbv.z; r.w=acc[3]+bbv.w;
      reinterpret_cast<float4*>(s_g1in)[j4] = r;
    }
    __syncthreads();
    // ---- F: scores (2 t-rows per wave, 8 fp16 cols per lane)
    {
      float q8r[8];
      #pragma unroll
      for (int j=0;j<8;j++) q8r[j] = s_q[cl*8+j];
      #pragma unroll 2
      for (int t0 = wid*2; t0 < T; t0 += 32){
        int t = t0 + half_id;
        float4 kv = *reinterpret_cast<const float4*>(keyb + (size_t)t*UU + cl*8);
        const h2* kh = reinterpret_cast<const h2*>(&kv);
        float s = 0.f;
        #pragma unroll
        for (int p=0;p<4;p++){
          s += ftanh((float)kh[p][0] + q8r[2*p  ])*v8r[2*p  ];
          s += ftanh((float)kh[p][1] + q8r[2*p+1])*v8r[2*p+1];
        }
        #pragma unroll
        for (int o=1;o<32;o<<=1) s += __shfl_xor(s, o);
        if (cl == 0) s_sc[t] = s;
      }
    }
    __syncthreads();
    // ---- G: softmax over t
    {
      float lm = -1e30f;
      for (int t = tid; t < T; t += 1024) lm = fmaxf(lm, s_sc[t]);
      #pragma unroll
      for (int o=32;o;o>>=1) lm = fmaxf(lm, __shfl_xor(lm, o));
      if (lane==0) s_wred[wid] = lm;
      __syncthreads();
      if (tid==0){
        float m = s_wred[0];
        #pragma unroll
        for (int w2=1; w2<16; ++w2) m = fmaxf(m, s_wred[w2]);
        s_scal[0] = m;
      }
      __syncthreads();
      float M = s_scal[0];
      float ls = 0.f;
      for (int t = tid; t < T; t += 1024){
        float e = __expf(s_sc[t]-M);
        s_sc[t] = e; ls += e;
      }
      #pragma unroll
      for (int o=32;o;o>>=1) ls += __shfl_xor(ls, o);
      if (lane==0) s_wred[wid] = ls;
      __syncthreads();
      if (tid==0){
        float s = 0.f;
        #pragma unroll
        for (int w2=0; w2<16; ++w2) s += s_wred[w2];
        s_scal[1] = 1.0f/s;
      }
      __syncthreads();
    }
    // ---- H: ctx partials (2 rows/wave) + tree reduce
    {
      float c8[8] = {0.f,0.f,0.f,0.f,0.f,0.f,0.f,0.f};
      #pragma unroll 2
      for (int t0 = wid*2; t0 < T; t0 += 32){
        int t = t0 + half_id;
        float wgt = s_sc[t];
        float4 mv = *reinterpret_cast<const float4*>(memb + (size_t)t*UU + cl*8);
        const h2* mh = reinterpret_cast<const h2*>(&mv);
        #pragma unroll
        for (int p=0;p<4;p++){
          c8[2*p  ] += wgt*(float)mh[p][0];
          c8[2*p+1] += wgt*(float)mh[p][1];
        }
      }
      #pragma unroll
      for (int j=0;j<8;j++) c8[j] += __shfl_xor(c8[j], 32);
      if (half_id == 0){
        float4 lo; lo.x=c8[0]; lo.y=c8[1]; lo.z=c8[2]; lo.w=c8[3];
        float4 hi; hi.x=c8[4]; hi.y=c8[5]; hi.z=c8[6]; hi.w=c8[7];
        *reinterpret_cast<float4*>(s_red + wid*UU + cl*8)     = lo;
        *reinterpret_cast<float4*>(s_red + wid*UU + cl*8 + 4) = hi;
      }
    }
    __syncthreads();
    if (tid < 128){
      float inv = s_scal[1];
      float s0=0.f, s1=0.f;
      #pragma unroll
      for (int w2=0; w2<16; ++w2){
        s0 += s_red[w2*UU + 2*tid];
        s1 += s_red[w2*UU + 2*tid+1];
      }
      h2 p; p[0]=(f16)(s0*inv); p[1]=(f16)(s1*inv);
      s_ctxh[tid] = p;
    }
    __syncthreads();
    // ---- I: g1in += Wproj[:, 256:] ctx  (rows k2=128..255)
    if (tid < 64){
      float acc[4]={0.f,0.f,0.f,0.f};
      gemv4h<256,64>(wts + O_WPROJ + 128u*256u, s_ctxh, tid, acc);
      float4 cur = reinterpret_cast<float4*>(s_g1in)[tid];
      cur.x+=acc[0]; cur.y+=acc[1]; cur.z+=acc[2]; cur.w+=acc[3];
      reinterpret_cast<float4*>(s_g1in)[tid] = cur;
      float tmp[4] = {cur.x, cur.y, cur.z, cur.w};
      pack2(s_g1inh, tid, tmp);
    }
    __syncthreads();
    // ---- J: gi = W1_ih g1in + b1_ih
    if (tid < 192){
      float acc[4]={0.f,0.f,0.f,0.f};
      gemv4h<256,192>(wts + O_W1IH, s_g1inh, tid, acc);
      const float4 bbv = reinterpret_cast<const float4*>(b1_ih)[tid];
      float4 r; r.x=acc[0]+bbv.x; r.y=acc[1]+bbv.y; r.z=acc[2]+bbv.z; r.w=acc[3]+bbv.w;
      reinterpret_cast<float4*>(s_gi)[tid] = r;
    }
    __syncthreads();
    // ---- K: gru1 -> g1h ; g2in = g1in + g1h
    if (tid < 128){
      float hn[2], g2[2];
      #pragma unroll
      for (int d=0; d<2; ++d){
        int e = 2*tid + d;
        float r = fsig(s_gi[e] + s_gh1[e]);
        float z = fsig(s_gi[256+e] + s_gh1[256+e]);
        float n = ftanh(s_gi[512+e] + r*s_gh1[512+e]);
        hn[d] = (1.f - z)*n + z*s_g1h[e];
        s_g1h[e] = hn[d];
        g2[d] = s_g1in[e] + hn[d];
        s_g2in[e] = g2[d];
      }
      h2 p; p[0]=(f16)hn[0]; p[1]=(f16)hn[1];
      s_g1hh[tid] = p;
      h2 q2; q2[0]=(f16)g2[0]; q2[1]=(f16)g2[1];
      s_g2inh[tid] = q2;
    }
    __syncthreads();
    // ---- L: gi = W2_ih g2in + b2_ih
    if (tid < 192){
      float acc[4]={0.f,0.f,0.f,0.f};
      gemv4h<256,192>(wts + O_W2IH, s_g2inh, tid, acc);
      const float4 bbv = reinterpret_cast<const float4*>(b2_ih)[tid];
      float4 r; r.x=acc[0]+bbv.x; r.y=acc[1]+bbv.y; r.z=acc[2]+bbv.z; r.w=acc[3]+bbv.w;
      reinterpret_cast<float4*>(s_gi)[tid] = r;
    }
    __syncthreads();
    // ---- M: gru2 -> g2h ; s2 = g2in + g2h
    if (tid < 128){
      float hn[2], s2[2];
      #pragma unroll
      for (int d=0; d<2; ++d){
        int e = 2*tid + d;
        float r = fsig(s_gi[e] + s_gh2[e]);
        float z = fsig(s_gi[256+e] + s_gh2[256+e]);
        float n = ftanh(s_gi[512+e] + r*s_gh2[512+e]);
        hn[d] = (1.f - z)*n + z*s_g2h[e];
        s_g2h[e] = hn[d];
        s2[d] = s_g2in[e] + hn[d];
      }
      h2 p; p[0]=(f16)hn[0]; p[1]=(f16)hn[1];
      s_g2hh[tid] = p;
      h2 q2; q2[0]=(f16)s2[0]; q2[1]=(f16)s2[1];
      s_s2h[tid] = q2;
    }
    __syncthreads();
    // ---- N: y = Wout s2 + bout; scatter; update prev
    if (tid < 100){
      float acc[4]={0.f,0.f,0.f,0.f};
      gemv4h<256,100>(wts + O_WOUT, s_s2h, tid, acc);
      const float4 bbv = reinterpret_cast<const float4*>(bout)[tid];
      float vals[4] = {acc[0]+bbv.x, acc[1]+bbv.y, acc[2]+bbv.z, acc[3]+bbv.w};
      #pragma unroll
      for (int d=0; d<4; ++d){
        int j = tid*4 + d;
        int mel = j/5, rr = j - mel*5;
        outb[(size_t)mel*(steps*RRR) + step*RRR + rr] = vals[d];
        if (rr == 4) s_prev[mel] = vals[d];
      }
    }
    __syncthreads();
  }
}

extern "C" void kernel_launch(void* const* d_in, const int* in_sizes, int n_in,
                              void* d_out, int out_size, void* d_ws, size_t ws_size,
                              hipStream_t stream)
{
  const float* mem  = (const float*)d_in[0];
  const float* Wp1  = (const float*)d_in[1];
  const float* bp1  = (const float*)d_in[2];
  const float* Wp2  = (const float*)d_in[3];
  const float* bp2  = (const float*)d_in[4];
  const float* W1   = (const float*)d_in[5];
  const float* W2   = (const float*)d_in[6];
  const float* vv   = (const float*)d_in[7];
  const float* Wa_ih= (const float*)d_in[8];
  const float* Wa_hh= (const float*)d_in[9];
  const float* ba_ih= (const float*)d_in[10];
  const float* ba_hh= (const float*)d_in[11];
  const float* W1_ih= (const float*)d_in[12];
  const float* W1_hh= (const float*)d_in[13];
  const float* b1_ih= (const float*)d_in[14];
  const float* b1_hh= (const float*)d_in[15];
  const float* W2_ih= (const float*)d_in[16];
  const float* W2_hh= (const float*)d_in[17];
  const float* b2_ih= (const float*)d_in[18];
  const float* b2_hh= (const float*)d_in[19];
  const float* Wproj= (const float*)d_in[20];
  const float* bproj= (const float*)d_in[21];
  const float* Wout = (const float*)d_in[22];
  const float* bout = (const float*)d_in[23];

  h2*  wsH2 = (h2*)d_ws;
  f16* wsF16= (f16*)d_ws;
  float* wsF = (float*)d_ws;
  int T = in_sizes[0] / (BB*UU);
  int steps = T / RRR;

  auto trh = [&](const float* src, unsigned off, int N, int K){
    int total = N*(K/2);
    k_tr_h<<<dim3((total+255)/256), dim3(256), 0, stream>>>(src, wsH2 + off, N, K);
  };
  trh(Wp1,   O_WP1T, 256, 80);
  trh(Wp2,   O_WP2T, 128, 256);
  trh(Wa_ih, O_WAIH, 768, 128);
  trh(Wa_hh, O_WAHH, 768, 256);
  trh(W2,    O_W2T,  256, 256);
  trh(Wproj, O_WPROJ,256, 512);
  trh(W1_ih, O_W1IH, 768, 256);
  trh(W1_hh, O_W1HH, 768, 256);
  trh(W2_ih, O_W2IH, 768, 256);
  trh(W2_hh, O_W2HH, 768, 256);
  trh(Wout,  O_WOUT, 400, 256);

  k_transpose<<<dim3((256*256+255)/256), dim3(256), 0, stream>>>(W1, wsF + OF_W1T, 256, 256);

  int n8 = (BB*T*UU)/8;
  k_memh<<<dim3((n8+255)/256), dim3(256), 0, stream>>>(mem, wsF16 + OH_MEM, n8);

  k_keys<<<dim3((T+127)/128, UU/128, BB), dim3(256), 0, stream>>>(mem, wsF + OF_W1T, wsF16 + OH_KEYS, T);

  k_decode<<<dim3(BB), dim3(1024), 0, stream>>>(wsH2, wsF16 + OH_KEYS, wsF16 + OH_MEM,
      bp1, bp2, vv, ba_ih, ba_hh, b1_ih, b1_hh, b2_ih, b2_hh, bproj, bout,
      (float*)d_out, T, steps);
}

// Round 5
// 19570.795 us; speedup vs baseline: 3.0223x; 3.0223x over previous
//
#include <hip/hip_runtime.h>

typedef _Float16 f16;
typedef _Float16 h2 __attribute__((ext_vector_type(2)));
typedef float fv4 __attribute__((ext_vector_type(4)));

#define BB 64
#define UU 256
#define RRR 5

// ---- h2-unit offsets (weights, pair-interleaved [K/2][N]); h2 = 4 bytes ----
constexpr size_t O_WP1T = 0;        // N=256 K=80   (10240 h2)
constexpr size_t O_WP2T = 10240;    // N=128 K=256  (16384)
constexpr size_t O_WAIH = 26624;    // N=768 K=128  (49152)
constexpr size_t O_WAHH = 75776;    // N=768 K=256  (98304)
constexpr size_t O_WQP  = 174080;   // N=512 K=256 (W2 | Wproj[:,0:256]) (65536)
constexpr size_t O_WPC  = 239616;   // N=256 K=256 (Wproj[:,256:512]) (32768)
constexpr size_t O_W1IH = 272384;   // N=768 K=256 (98304)
constexpr size_t O_W1HH = 370688;
constexpr size_t O_W2IH = 468992;
constexpr size_t O_W2HH = 567296;
constexpr size_t O_WOUT = 665600;   // N=400 K=256 (51200) -> weights end 716800 h2 = 2,867,200 B
// ---- float-unit offsets (float = 4 bytes, same granularity as h2) ----
constexpr size_t OF_BQP = 716800;   // 512 floats (0|bproj) -> end 717312
constexpr size_t OF_W1T = 717312;   // 65536 floats -> end 782848 f = 3,131,392 B
// ---- half-unit offsets (half = 2 bytes) ----
constexpr size_t OH_KEYS = 1565696;             // byte 3,131,392; 64*1000*256 halfs
constexpr size_t OH_MEM  = OH_KEYS + 16384000;  // byte 35,899,392 -> end ~68.7 MB

#if defined(__has_builtin)
#if __has_builtin(__builtin_amdgcn_fdot2)
#define USE_FDOT2 1
#endif
#endif

__device__ __forceinline__ float dot2f(h2 a, h2 b, float c){
#ifdef USE_FDOT2
  return __builtin_amdgcn_fdot2(a, b, c, false);
#else
  return c + (float)a[0]*(float)b[0] + (float)a[1]*(float)b[1];
#endif
}

__device__ __forceinline__ float fsig(float x){ return 1.0f/(1.0f+__expf(-x)); }
__device__ __forceinline__ float ftanh(float x){ return 1.0f - 2.0f/(1.0f+__expf(2.0f*x)); }

// ---------------- setup kernels ----------------
// src [N][srcK] fp32; extract K cols starting at kbase; dst pair-interleaved
// [K/2][Ntot] h2 at column offset coloff.
__global__ void k_tr_hx(const float* __restrict__ src, int srcK, int kbase,
                        h2* __restrict__ dst, int N, int K, int Ntot, int coloff){
  int idx = blockIdx.x*blockDim.x + threadIdx.x;
  int tot = N*(K/2);
  if (idx < tot){
    int k2 = idx / N, n = idx - k2*N;
    h2 p; p[0]=(f16)src[n*srcK + kbase + 2*k2]; p[1]=(f16)src[n*srcK + kbase + 2*k2+1];
    dst[(size_t)k2*Ntot + coloff + n] = p;
  }
}

__global__ void k_transpose(const float* __restrict__ src, float* __restrict__ dst, int N, int K){
  int idx = blockIdx.x*blockDim.x + threadIdx.x;
  if (idx < N*K){
    int n = idx / K, k = idx - n*K;
    dst[k*N + n] = src[idx];
  }
}

__global__ void k_biasqp(const float* __restrict__ bproj, float* __restrict__ dst){
  int i = blockIdx.x*blockDim.x + threadIdx.x;
  if (i < 512) dst[i] = (i < 256) ? 0.f : bproj[i-256];
}

__global__ void k_memh(const float* __restrict__ src, f16* __restrict__ dst, int n8){
  int i = blockIdx.x*blockDim.x + threadIdx.x;
  if (i < n8){
    const float4* s = reinterpret_cast<const float4*>(src) + 2*(size_t)i;
    float4 f0 = s[0], f1 = s[1];
    union { f16 h[8]; float4 v; } u;
    u.h[0]=(f16)f0.x; u.h[1]=(f16)f0.y; u.h[2]=(f16)f0.z; u.h[3]=(f16)f0.w;
    u.h[4]=(f16)f1.x; u.h[5]=(f16)f1.y; u.h[6]=(f16)f1.z; u.h[7]=(f16)f1.w;
    reinterpret_cast<float4*>(dst)[i] = u.v;
  }
}

// keys[b][t][c] = sum_u mem[b][t][u]*W1[c][u]; W1t fp32 [u][c]; output fp16
__global__ __launch_bounds__(256) void k_keys(const float* __restrict__ mem,
      const float* __restrict__ W1t, f16* __restrict__ keys, int T)
{
  const int b = blockIdx.z;
  const int tbase = blockIdx.x * 128;
  const int cbase = blockIdx.y * 128;
  const int tid = threadIdx.x;
  const int rt = tid >> 4, ct = tid & 15;
  const float* memb = mem + (size_t)b*T*UU;

  float acc[8][8];
  #pragma unroll
  for (int i=0;i<8;i++){
    #pragma unroll
    for (int j=0;j<8;j++) acc[i][j]=0.f;
  }
  const float* arow[8];
  #pragma unroll
  for (int i=0;i<8;i++){
    int t = tbase + rt*8 + i;
    arow[i] = memb + (size_t)(t < T ? t : T-1)*UU;
  }
  const float* wcol = W1t + cbase + ct*8;

  for (int k=0;k<UU;k+=4){
    float w8[4][8];
    #pragma unroll
    for (int kk=0;kk<4;kk++){
      float4 lo = *reinterpret_cast<const float4*>(wcol + (size_t)(k+kk)*UU);
      float4 hi = *reinterpret_cast<const float4*>(wcol + (size_t)(k+kk)*UU + 4);
      w8[kk][0]=lo.x; w8[kk][1]=lo.y; w8[kk][2]=lo.z; w8[kk][3]=lo.w;
      w8[kk][4]=hi.x; w8[kk][5]=hi.y; w8[kk][6]=hi.z; w8[kk][7]=hi.w;
    }
    #pragma unroll
    for (int i=0;i<8;i++){
      float4 a = *reinterpret_cast<const float4*>(arow[i] + k);
      float a4[4] = {a.x, a.y, a.z, a.w};
      #pragma unroll
      for (int kk=0;kk<4;kk++){
        #pragma unroll
        for (int j=0;j<8;j++) acc[i][j] += a4[kk]*w8[kk][j];
      }
    }
  }
  #pragma unroll
  for (int i=0;i<8;i++){
    int t = tbase + rt*8 + i;
    if (t < T){
      f16* dst = keys + (size_t)b*T*UU + (size_t)t*UU + cbase + ct*8;
      union { f16 h[8]; float4 v; } u;
      #pragma unroll
      for (int j=0;j<8;j++) u.h[j] = (f16)acc[i][j];
      *reinterpret_cast<float4*>(dst) = u.v;
    }
  }
}

// ---------------- generic GEMV engine (shared code for all stages) ----------------
// W: [K2 rows][Nf4 float4/row] (pair-interleaved h2). in: h2[K2] (LDS).
// Thread map: j4 = tid & (2^j4shift - 1), ks = tid >> j4shift, ksn = 1024 >> j4shift.
// act: 0 = +bias, 1 = relu(+bias), 2 = accumulate into dest (no bias).
__device__ __attribute__((noinline)) void gemv_stage(
    const h2* __restrict__ W, const h2* __restrict__ in,
    const float* __restrict__ bias, float* __restrict__ dest, h2* __restrict__ desth,
    float* __restrict__ spart, int K2, int Nf4, int j4shift, int act, int tid)
{
  const int j4cap = 1 << j4shift;
  const int ksn   = 1024 >> j4shift;
  const int j4 = tid & (j4cap - 1);
  const int ks = tid >> j4shift;
  float4* part4 = reinterpret_cast<float4*>(spart);
  if (j4 < Nf4){
    int k2a = (K2 * ks) / ksn;
    int k2b = (K2 * (ks+1)) / ksn;
    const float4* w = reinterpret_cast<const float4*>(W) + (size_t)k2a * Nf4 + j4;
    float a0=0.f, a1=0.f, a2=0.f, a3=0.f;
    #pragma unroll 4
    for (int k2 = k2a; k2 < k2b; ++k2){
      float4 wp = *w; w += Nf4;
      h2 a = in[k2];
      const h2* wh = reinterpret_cast<const h2*>(&wp);
      a0 = dot2f(wh[0], a, a0);
      a1 = dot2f(wh[1], a, a1);
      a2 = dot2f(wh[2], a, a2);
      a3 = dot2f(wh[3], a, a3);
    }
    float4 r; r.x=a0; r.y=a1; r.z=a2; r.w=a3;
    part4[ks * j4cap + j4] = r;
  }
  __syncthreads();
  if (tid < Nf4){
    float4 s = part4[tid];
    for (int k = 1; k < ksn; ++k){
      float4 p = part4[k * j4cap + tid];
      s.x+=p.x; s.y+=p.y; s.z+=p.z; s.w+=p.w;
    }
    if (bias){
      float4 bv = reinterpret_cast<const float4*>(bias)[tid];
      s.x+=bv.x; s.y+=bv.y; s.z+=bv.z; s.w+=bv.w;
    }
    if (act == 1){
      s.x=fmaxf(s.x,0.f); s.y=fmaxf(s.y,0.f); s.z=fmaxf(s.z,0.f); s.w=fmaxf(s.w,0.f);
    } else if (act == 2){
      float4 d = reinterpret_cast<float4*>(dest)[tid];
      s.x+=d.x; s.y+=d.y; s.z+=d.z; s.w+=d.w;
    }
    if (dest) reinterpret_cast<float4*>(dest)[tid] = s;
    if (desth){
      h2 p0; p0[0]=(f16)s.x; p0[1]=(f16)s.y;
      h2 p1; p1[0]=(f16)s.z; p1[1]=(f16)s.w;
      desth[2*tid] = p0; desth[2*tid+1] = p1;
    }
  }
  __syncthreads();
}

// GRU gate fuse: h = (1-z)*n + z*h; optional sum = addsrc + h_new.
__device__ __attribute__((noinline)) void gru_gate(
    const float* __restrict__ gi, const float* __restrict__ gh,
    float* __restrict__ h, h2* __restrict__ hh2,
    const float* __restrict__ addsrc, float* __restrict__ sumf,
    h2* __restrict__ sumh, int tid)
{
  if (tid < 128){
    float hn[2], sm[2] = {0.f, 0.f};
    #pragma unroll
    for (int d=0; d<2; ++d){
      int e = 2*tid + d;
      float r = fsig(gi[e] + gh[e]);
      float z = fsig(gi[256+e] + gh[256+e]);
      float n = ftanh(gi[512+e] + r*gh[512+e]);
      hn[d] = (1.f - z)*n + z*h[e];
      h[e] = hn[d];
      if (addsrc){ sm[d] = addsrc[e] + hn[d]; if (sumf) sumf[e] = sm[d]; }
    }
    h2 p; p[0]=(f16)hn[0]; p[1]=(f16)hn[1];
    hh2[tid] = p;
    if (addsrc && sumh){ h2 q; q[0]=(f16)sm[0]; q[1]=(f16)sm[1]; sumh[tid] = q; }
  }
  __syncthreads();
}

// ---------------- persistent decoder ----------------
__global__ __launch_bounds__(1024) void k_decode(
    const h2* __restrict__ wts, const float* __restrict__ wsf,
    const f16* __restrict__ keysg, const f16* __restrict__ memg,
    const float* __restrict__ bp1, const float* __restrict__ bp2,
    const float* __restrict__ vvec,
    const float* __restrict__ ba_ih, const float* __restrict__ ba_hh,
    const float* __restrict__ b1_ih, const float* __restrict__ b1_hh,
    const float* __restrict__ b2_ih, const float* __restrict__ b2_hh,
    const float* __restrict__ bout,
    float* __restrict__ out, int T, int steps)
{
  __shared__ __align__(16) float s_part[4096];   // gemv partials / ctx partials
  __shared__ __align__(16) float s_sc[1024];     // exp(scores)
  __shared__ __align__(16) float s_gi[768];
  __shared__ __align__(16) float s_gh[768];      // Wa_hh result
  __shared__ __align__(16) float s_gh1[768];
  __shared__ __align__(16) float s_gh2[768];
  __shared__ __align__(16) float s_q[512];       // [0:256]=q, [256:512]=g1in
  __shared__ __align__(16) float s_ha[256];
  __shared__ __align__(16) float s_g1h[256];
  __shared__ __align__(16) float s_g2h[256];
  __shared__ __align__(16) float s_g2in[256];
  __shared__ __align__(16) float s_y[400];
  __shared__ __align__(16) f16   s_prevf[80];
  __shared__ __align__(16) h2    s_hah[128], s_g1hh[128], s_g2hh[128];
  __shared__ __align__(16) h2    s_g1inh[128], s_g2inh[128], s_s2h[128];
  __shared__ __align__(16) h2    s_x1h[128], s_xh[64], s_ctxh[128];
  __shared__ float s_wred[16];
  __shared__ float s_scal[1];

  const int b = blockIdx.x;
  const int tid = threadIdx.x;
  const int lane = tid & 63;
  const int wid = tid >> 6;
  const int half_id = lane >> 5;
  const int cl = lane & 31;

  const f16* keyb = keysg + (size_t)b*T*UU;
  const f16* memb = memg  + (size_t)b*T*UU;
  float* outb = out + (size_t)b*80*(steps*RRR);

  if (tid < 128){
    s_ha[2*tid]=0.f; s_ha[2*tid+1]=0.f;
    s_g1h[2*tid]=0.f; s_g1h[2*tid+1]=0.f;
    s_g2h[2*tid]=0.f; s_g2h[2*tid+1]=0.f;
    h2 z; z[0]=(f16)0.f; z[1]=(f16)0.f;
    s_hah[tid]=z; s_g1hh[tid]=z; s_g2hh[tid]=z;
  }
  if (tid < 80) s_prevf[tid] = (f16)0.f;
  __syncthreads();

  float v8[8];
  #pragma unroll
  for (int j=0;j<8;j++) v8[j] = vvec[cl*8+j];

  for (int step = 0; step < steps; ++step){
    // -- hh GEMVs (state from step start) --
    gemv_stage(wts+O_WAHH, s_hah,  ba_hh, s_gh,  nullptr, s_part, 128, 192, 8, 0, tid);
    gemv_stage(wts+O_W1HH, s_g1hh, b1_hh, s_gh1, nullptr, s_part, 128, 192, 8, 0, tid);
    gemv_stage(wts+O_W2HH, s_g2hh, b2_hh, s_gh2, nullptr, s_part, 128, 192, 8, 0, tid);
    // -- prenet --
    gemv_stage(wts+O_WP1T, reinterpret_cast<const h2*>(s_prevf), bp1, nullptr, s_x1h,
               s_part, 40, 64, 6, 1, tid);
    gemv_stage(wts+O_WP2T, s_x1h, bp2, nullptr, s_xh, s_part, 128, 32, 5, 1, tid);
    // -- attn GRU input + gates --
    gemv_stage(wts+O_WAIH, s_xh, ba_ih, s_gi, nullptr, s_part, 64, 192, 8, 0, tid);
    gru_gate(s_gi, s_gh, s_ha, s_hah, nullptr, nullptr, nullptr, tid);
    // -- q | g1in(d_t part) fused --
    gemv_stage(wts+O_WQP, s_hah, wsf+OF_BQP, s_q, nullptr, s_part, 128, 128, 7, 0, tid);

    // -- attention: scores -> exp -> sum (fused), then weighted context --
    {
      float q8[8];
      #pragma unroll
      for (int j=0;j<8;j++) q8[j] = s_q[cl*8+j];
      float rs = 0.f;
      for (int t0 = wid*2; t0 < T; t0 += 32){
        int t = t0 + half_id;
        fv4 kv = __builtin_nontemporal_load(
            reinterpret_cast<const fv4*>(keyb + (size_t)t*UU) + cl);
        const h2* kh = reinterpret_cast<const h2*>(&kv);
        float s = 0.f;
        #pragma unroll
        for (int p=0;p<4;p++){
          s += ftanh((float)kh[p][0] + q8[2*p  ])*v8[2*p  ];
          s += ftanh((float)kh[p][1] + q8[2*p+1])*v8[2*p+1];
        }
        #pragma unroll
        for (int o=1;o<32;o<<=1) s += __shfl_xor(s, o);
        float e = __expf(s);     // |score| <= ||v||_1 ~ 13, safe without max-sub
        if (cl==0) s_sc[t] = e;
        rs += e;
      }
      rs += __shfl_xor(rs, 32);
      if (lane==0) s_wred[wid] = rs;
    }
    __syncthreads();
    if (tid==0){
      float tot = 0.f;
      #pragma unroll
      for (int w=0; w<16; ++w) tot += s_wred[w];
      s_scal[0] = 1.0f/tot;
    }
    {
      float c8[8] = {0.f,0.f,0.f,0.f,0.f,0.f,0.f,0.f};
      for (int t0 = wid*2; t0 < T; t0 += 32){
        int t = t0 + half_id;
        float wgt = s_sc[t];
        fv4 mv = __builtin_nontemporal_load(
            reinterpret_cast<const fv4*>(memb + (size_t)t*UU) + cl);
        const h2* mh = reinterpret_cast<const h2*>(&mv);
        #pragma unroll
        for (int p=0;p<4;p++){
          c8[2*p  ] += wgt*(float)mh[p][0];
          c8[2*p+1] += wgt*(float)mh[p][1];
        }
      }
      #pragma unroll
      for (int j=0;j<8;j++) c8[j] += __shfl_xor(c8[j], 32);
      if (half_id == 0){
        float4 lo; lo.x=c8[0]; lo.y=c8[1]; lo.z=c8[2]; lo.w=c8[3];
        float4 hi; hi.x=c8[4]; hi.y=c8[5]; hi.z=c8[6]; hi.w=c8[7];
        *reinterpret_cast<float4*>(s_part + wid*256 + cl*8)     = lo;
        *reinterpret_cast<float4*>(s_part + wid*256 + cl*8 + 4) = hi;
      }
    }
    __syncthreads();
    if (tid < 128){
      float inv = s_scal[0];
      float a = 0.f, bsum = 0.f;
      #pragma unroll
      for (int w=0; w<16; ++w){
        a    += s_part[w*256 + 2*tid];
        bsum += s_part[w*256 + 2*tid+1];
      }
      h2 p; p[0]=(f16)(a*inv); p[1]=(f16)(bsum*inv);
      s_ctxh[tid] = p;
    }
    __syncthreads();

    // -- g1in += Wproj_ctx * ctx ; pack g1inh --
    gemv_stage(wts+O_WPC, s_ctxh, nullptr, s_q+256, s_g1inh, s_part, 128, 64, 6, 2, tid);
    // -- GRU1 --
    gemv_stage(wts+O_W1IH, s_g1inh, b1_ih, s_gi, nullptr, s_part, 128, 192, 8, 0, tid);
    gru_gate(s_gi, s_gh1, s_g1h, s_g1hh, s_q+256, s_g2in, s_g2inh, tid);
    // -- GRU2 --
    gemv_stage(wts+O_W2IH, s_g2inh, b2_ih, s_gi, nullptr, s_part, 128, 192, 8, 0, tid);
    gru_gate(s_gi, s_gh2, s_g2h, s_g2hh, s_g2in, nullptr, s_s2h, tid);
    // -- output projection --
    gemv_stage(wts+O_WOUT, s_s2h, bout, s_y, nullptr, s_part, 128, 100, 7, 0, tid);
    // -- scatter + prev update --
    if (tid < 400){
      float val = s_y[tid];
      int mel = tid / 5, rr = tid - mel*5;
      __builtin_nontemporal_store(val, &outb[(size_t)mel*(steps*RRR) + step*RRR + rr]);
      if (rr == 4) s_prevf[mel] = (f16)val;
    }
    __syncthreads();
  }
}

extern "C" void kernel_launch(void* const* d_in, const int* in_sizes, int n_in,
                              void* d_out, int out_size, void* d_ws, size_t ws_size,
                              hipStream_t stream)
{
  const float* mem  = (const float*)d_in[0];
  const float* Wp1  = (const float*)d_in[1];
  const float* bp1  = (const float*)d_in[2];
  const float* Wp2  = (const float*)d_in[3];
  const float* bp2  = (const float*)d_in[4];
  const float* W1   = (const float*)d_in[5];
  const float* W2   = (const float*)d_in[6];
  const float* vv   = (const float*)d_in[7];
  const float* Wa_ih= (const float*)d_in[8];
  const float* Wa_hh= (const float*)d_in[9];
  const float* ba_ih= (const float*)d_in[10];
  const float* ba_hh= (const float*)d_in[11];
  const float* W1_ih= (const float*)d_in[12];
  const float* W1_hh= (const float*)d_in[13];
  const float* b1_ih= (const float*)d_in[14];
  const float* b1_hh= (const float*)d_in[15];
  const float* W2_ih= (const float*)d_in[16];
  const float* W2_hh= (const float*)d_in[17];
  const float* b2_ih= (const float*)d_in[18];
  const float* b2_hh= (const float*)d_in[19];
  const float* Wproj= (const float*)d_in[20];
  const float* bproj= (const float*)d_in[21];
  const float* Wout = (const float*)d_in[22];
  const float* bout = (const float*)d_in[23];

  h2*  wsH2 = (h2*)d_ws;
  f16* wsF16= (f16*)d_ws;
  float* wsF = (float*)d_ws;
  int T = in_sizes[0] / (BB*UU);
  int steps = T / RRR;

  auto tr = [&](const float* src, int srcK, int kbase, size_t off, int N, int K,
                int Ntot, int coloff){
    int total = N*(K/2);
    k_tr_hx<<<dim3((total+255)/256), dim3(256), 0, stream>>>(
        src, srcK, kbase, wsH2 + off, N, K, Ntot, coloff);
  };
  tr(Wp1,   80,  0, O_WP1T, 256, 80,  256, 0);
  tr(Wp2,   256, 0, O_WP2T, 128, 256, 128, 0);
  tr(Wa_ih, 128, 0, O_WAIH, 768, 128, 768, 0);
  tr(Wa_hh, 256, 0, O_WAHH, 768, 256, 768, 0);
  tr(W2,    256, 0, O_WQP,  256, 256, 512, 0);
  tr(Wproj, 512, 0, O_WQP,  256, 256, 512, 256);
  tr(Wproj, 512, 256, O_WPC, 256, 256, 256, 0);
  tr(W1_ih, 256, 0, O_W1IH, 768, 256, 768, 0);
  tr(W1_hh, 256, 0, O_W1HH, 768, 256, 768, 0);
  tr(W2_ih, 256, 0, O_W2IH, 768, 256, 768, 0);
  tr(W2_hh, 256, 0, O_W2HH, 768, 256, 768, 0);
  tr(Wout,  256, 0, O_WOUT, 400, 256, 400, 0);

  k_biasqp<<<dim3(2), dim3(256), 0, stream>>>(bproj, wsF + OF_BQP);
  k_transpose<<<dim3((256*256+255)/256), dim3(256), 0, stream>>>(W1, wsF + OF_W1T, 256, 256);

  int n8 = (BB*T*UU)/8;
  k_memh<<<dim3((n8+255)/256), dim3(256), 0, stream>>>(mem, wsF16 + OH_MEM, n8);
  k_keys<<<dim3((T+127)/128, UU/128, BB), dim3(256), 0, stream>>>(mem, wsF + OF_W1T, wsF16 + OH_KEYS, T);

  k_decode<<<dim3(BB), dim3(1024), 0, stream>>>(wsH2, wsF,
      wsF16 + OH_KEYS, wsF16 + OH_MEM,
      bp1, bp2, vv, ba_ih, ba_hh, b1_ih, b1_hh, b2_ih, b2_hh, bout,
      (float*)d_out, T, steps);
}

// Round 6
// 12555.557 us; speedup vs baseline: 4.7110x; 1.5587x over previous
//
#include <hip/hip_runtime.h>

typedef _Float16 f16;
typedef _Float16 h2 __attribute__((ext_vector_type(2)));
typedef float fv4 __attribute__((ext_vector_type(4)));

#define BB 64
#define UU 256
#define RRR 5
#define NQUAD 4

// ---- h2-unit offsets (weights, pair-interleaved [K/2][N]); h2 = 4 bytes ----
constexpr size_t O_WP1T = 0;        // N=256 K=80
constexpr size_t O_WP2T = 10240;    // N=128 K=256
constexpr size_t O_WAIH = 26624;    // N=768 K=128
constexpr size_t O_WAHH = 75776;    // N=768 K=256
constexpr size_t O_WQP  = 174080;   // N=512 K=256 (W2*2log2e | Wproj[:,0:256])
constexpr size_t O_WPC  = 239616;   // N=256 K=256 (Wproj[:,256:512])
constexpr size_t O_W1IH = 272384;   // N=768 K=256
constexpr size_t O_W1HH = 370688;
constexpr size_t O_W2IH = 468992;
constexpr size_t O_W2HH = 567296;
constexpr size_t O_WOUT = 665600;   // N=400 K=256 -> weights end 716800 h2 = 2,867,200 B
// ---- float-unit offsets ----
constexpr size_t OF_BQP = 716800;   // 512 floats (0|bproj)
constexpr size_t OF_W1T = 717312;   // 65536 floats -> end 782848 f = 3,131,392 B
// ---- half-unit offsets ----
constexpr size_t OH_KEYS = 1565696;             // byte 3,131,392; 64*1000*256 halfs (pre-scaled by 2log2e)
constexpr size_t OH_MEM  = OH_KEYS + 16384000;  // byte 35,899,392; 64*1000*256 halfs -> end byte 68,667,392
// ---- cross-block exchange (float/int units) ----
constexpr size_t OF_CTXP  = 17166848;  // ctx_part [64][2][4][256] floats (131072)
constexpr size_t OF_ESUM  = 17297920;  // esum     [64][2][4] floats (512)
constexpr size_t OI_FLAGS = 17298432;  // flags    [64][256] ints (16384) -> end ~69.26 MB

#define SCL2LOG2E 2.8853900817779268f

#if defined(__has_builtin)
#if __has_builtin(__builtin_amdgcn_fdot2)
#define USE_FDOT2 1
#endif
#endif

__device__ __forceinline__ float dot2f(h2 a, h2 b, float c){
#ifdef USE_FDOT2
  return __builtin_amdgcn_fdot2(a, b, c, false);
#else
  return c + (float)a[0]*(float)b[0] + (float)a[1]*(float)b[1];
#endif
}

__device__ __forceinline__ float frcp(float x){ return __builtin_amdgcn_rcpf(x); }
__device__ __forceinline__ float fexp2(float x){ return __builtin_amdgcn_exp2f(x); }
__device__ __forceinline__ float fsig(float x){ return frcp(1.0f + fexp2(-1.4426950408889634f*x)); }
__device__ __forceinline__ float ftanh(float x){ return 1.0f - 2.0f*frcp(1.0f + fexp2(SCL2LOG2E*x)); }

// ---------------- setup kernels ----------------
__global__ void k_tr_hx(const float* __restrict__ src, int srcK, int kbase,
                        h2* __restrict__ dst, int N, int K, int Ntot, int coloff,
                        float scale){
  int idx = blockIdx.x*blockDim.x + threadIdx.x;
  int tot = N*(K/2);
  if (idx < tot){
    int k2 = idx / N, n = idx - k2*N;
    h2 p; p[0]=(f16)(scale*src[n*srcK + kbase + 2*k2]);
    p[1]=(f16)(scale*src[n*srcK + kbase + 2*k2+1]);
    dst[(size_t)k2*Ntot + coloff + n] = p;
  }
}

__global__ void k_transpose(const float* __restrict__ src, float* __restrict__ dst, int N, int K){
  int idx = blockIdx.x*blockDim.x + threadIdx.x;
  if (idx < N*K){
    int n = idx / K, k = idx - n*K;
    dst[k*N + n] = src[idx];
  }
}

__global__ void k_biasqp(const float* __restrict__ bproj, float* __restrict__ dst){
  int i = blockIdx.x*blockDim.x + threadIdx.x;
  if (i < 512) dst[i] = (i < 256) ? 0.f : bproj[i-256];
}

__global__ void k_zero(int* __restrict__ p, int n){
  int i = blockIdx.x*blockDim.x + threadIdx.x;
  if (i < n) p[i] = 0;
}

__global__ void k_memh(const float* __restrict__ src, f16* __restrict__ dst, int n8){
  int i = blockIdx.x*blockDim.x + threadIdx.x;
  if (i < n8){
    const float4* s = reinterpret_cast<const float4*>(src) + 2*(size_t)i;
    float4 f0 = s[0], f1 = s[1];
    union { f16 h[8]; float4 v; } u;
    u.h[0]=(f16)f0.x; u.h[1]=(f16)f0.y; u.h[2]=(f16)f0.z; u.h[3]=(f16)f0.w;
    u.h[4]=(f16)f1.x; u.h[5]=(f16)f1.y; u.h[6]=(f16)f1.z; u.h[7]=(f16)f1.w;
    reinterpret_cast<float4*>(dst)[i] = u.v;
  }
}

// keys[b][t][c] = 2log2e * sum_u mem[b][t][u]*W1[c][u]; fp16 out
__global__ __launch_bounds__(256) void k_keys(const float* __restrict__ mem,
      const float* __restrict__ W1t, f16* __restrict__ keys, int T)
{
  const int b = blockIdx.z;
  const int tbase = blockIdx.x * 128;
  const int cbase = blockIdx.y * 128;
  const int tid = threadIdx.x;
  const int rt = tid >> 4, ct = tid & 15;
  const float* memb = mem + (size_t)b*T*UU;

  float acc[8][8];
  #pragma unroll
  for (int i=0;i<8;i++){
    #pragma unroll
    for (int j=0;j<8;j++) acc[i][j]=0.f;
  }
  const float* arow[8];
  #pragma unroll
  for (int i=0;i<8;i++){
    int t = tbase + rt*8 + i;
    arow[i] = memb + (size_t)(t < T ? t : T-1)*UU;
  }
  const float* wcol = W1t + cbase + ct*8;

  for (int k=0;k<UU;k+=4){
    float w8[4][8];
    #pragma unroll
    for (int kk=0;kk<4;kk++){
      float4 lo = *reinterpret_cast<const float4*>(wcol + (size_t)(k+kk)*UU);
      float4 hi = *reinterpret_cast<const float4*>(wcol + (size_t)(k+kk)*UU + 4);
      w8[kk][0]=lo.x; w8[kk][1]=lo.y; w8[kk][2]=lo.z; w8[kk][3]=lo.w;
      w8[kk][4]=hi.x; w8[kk][5]=hi.y; w8[kk][6]=hi.z; w8[kk][7]=hi.w;
    }
    #pragma unroll
    for (int i=0;i<8;i++){
      float4 a = *reinterpret_cast<const float4*>(arow[i] + k);
      float a4[4] = {a.x, a.y, a.z, a.w};
      #pragma unroll
      for (int kk=0;kk<4;kk++){
        #pragma unroll
        for (int j=0;j<8;j++) acc[i][j] += a4[kk]*w8[kk][j];
      }
    }
  }
  #pragma unroll
  for (int i=0;i<8;i++){
    int t = tbase + rt*8 + i;
    if (t < T){
      f16* dst = keys + (size_t)b*T*UU + (size_t)t*UU + cbase + ct*8;
      union { f16 h[8]; float4 v; } u;
      #pragma unroll
      for (int j=0;j<8;j++) u.h[j] = (f16)(acc[i][j]*SCL2LOG2E);
      *reinterpret_cast<float4*>(dst) = u.v;
    }
  }
}

// ---------------- generic GEMV engine ----------------
__device__ __attribute__((noinline)) void gemv_stage(
    const h2* __restrict__ W, const h2* __restrict__ in,
    const float* __restrict__ bias, float* __restrict__ dest, h2* __restrict__ desth,
    float* __restrict__ spart, int K2, int Nf4, int j4shift, int act, int tid)
{
  const int j4cap = 1 << j4shift;
  const int ksn   = 1024 >> j4shift;
  const int j4 = tid & (j4cap - 1);
  const int ks = tid >> j4shift;
  float4* part4 = reinterpret_cast<float4*>(spart);
  if (j4 < Nf4){
    int k2a = (K2 * ks) / ksn;
    int k2b = (K2 * (ks+1)) / ksn;
    const float4* w = reinterpret_cast<const float4*>(W) + (size_t)k2a * Nf4 + j4;
    float a0=0.f, a1=0.f, a2=0.f, a3=0.f;
    #pragma unroll 4
    for (int k2 = k2a; k2 < k2b; ++k2){
      float4 wp = *w; w += Nf4;
      h2 a = in[k2];
      const h2* wh = reinterpret_cast<const h2*>(&wp);
      a0 = dot2f(wh[0], a, a0);
      a1 = dot2f(wh[1], a, a1);
      a2 = dot2f(wh[2], a, a2);
      a3 = dot2f(wh[3], a, a3);
    }
    float4 r; r.x=a0; r.y=a1; r.z=a2; r.w=a3;
    part4[ks * j4cap + j4] = r;
  }
  __syncthreads();
  if (tid < Nf4){
    float4 s = part4[tid];
    for (int k = 1; k < ksn; ++k){
      float4 p = part4[k * j4cap + tid];
      s.x+=p.x; s.y+=p.y; s.z+=p.z; s.w+=p.w;
    }
    if (bias){
      float4 bv = reinterpret_cast<const float4*>(bias)[tid];
      s.x+=bv.x; s.y+=bv.y; s.z+=bv.z; s.w+=bv.w;
    }
    if (act == 1){
      s.x=fmaxf(s.x,0.f); s.y=fmaxf(s.y,0.f); s.z=fmaxf(s.z,0.f); s.w=fmaxf(s.w,0.f);
    } else if (act == 2){
      float4 d = reinterpret_cast<float4*>(dest)[tid];
      s.x+=d.x; s.y+=d.y; s.z+=d.z; s.w+=d.w;
    }
    if (dest) reinterpret_cast<float4*>(dest)[tid] = s;
    if (desth){
      h2 p0; p0[0]=(f16)s.x; p0[1]=(f16)s.y;
      h2 p1; p1[0]=(f16)s.z; p1[1]=(f16)s.w;
      desth[2*tid] = p0; desth[2*tid+1] = p1;
    }
  }
  __syncthreads();
}

__device__ __attribute__((noinline)) void gru_gate(
    const float* __restrict__ gi, const float* __restrict__ gh,
    float* __restrict__ h, h2* __restrict__ hh2,
    const float* __restrict__ addsrc, float* __restrict__ sumf,
    h2* __restrict__ sumh, int tid)
{
  if (tid < 128){
    float hn[2], sm[2] = {0.f, 0.f};
    #pragma unroll
    for (int d=0; d<2; ++d){
      int e = 2*tid + d;
      float r = fsig(gi[e] + gh[e]);
      float z = fsig(gi[256+e] + gh[256+e]);
      float n = ftanh(gi[512+e] + r*gh[512+e]);
      hn[d] = (1.f - z)*n + z*h[e];
      h[e] = hn[d];
      if (addsrc){ sm[d] = addsrc[e] + hn[d]; if (sumf) sumf[e] = sm[d]; }
    }
    h2 p; p[0]=(f16)hn[0]; p[1]=(f16)hn[1];
    hh2[tid] = p;
    if (addsrc && sumh){ h2 q; q[0]=(f16)sm[0]; q[1]=(f16)sm[1]; sumh[tid] = q; }
  }
  __syncthreads();
}

// ---------------- persistent decoder: 4 blocks per batch element ----------------
// quad q computes the full (replicated, bitwise-identical) GEMV chain, but only
// T/4 of the attention sweep; one device-scope sync per step exchanges partials.
__global__ __launch_bounds__(1024) void k_decode(
    const h2* __restrict__ wts, const float* __restrict__ wsf,
    const f16* __restrict__ keysg, const f16* __restrict__ memg,
    float* __restrict__ ctxp, float* __restrict__ esum, int* __restrict__ flags,
    const float* __restrict__ bp1, const float* __restrict__ bp2,
    const float* __restrict__ vvec,
    const float* __restrict__ ba_ih, const float* __restrict__ ba_hh,
    const float* __restrict__ b1_ih, const float* __restrict__ b1_hh,
    const float* __restrict__ b2_ih, const float* __restrict__ b2_hh,
    const float* __restrict__ bout,
    float* __restrict__ out, int T, int steps)
{
  __shared__ __align__(16) float s_part[4096];
  __shared__ __align__(16) float s_sc[1024];
  __shared__ __align__(16) float s_gi[768];
  __shared__ __align__(16) float s_gh[768];
  __shared__ __align__(16) float s_gh1[768];
  __shared__ __align__(16) float s_gh2[768];
  __shared__ __align__(16) float s_q[512];
  __shared__ __align__(16) float s_ha[256];
  __shared__ __align__(16) float s_g1h[256];
  __shared__ __align__(16) float s_g2h[256];
  __shared__ __align__(16) float s_g2in[256];
  __shared__ __align__(16) float s_y[400];
  __shared__ __align__(16) f16   s_prevf[80];
  __shared__ __align__(16) h2    s_hah[128], s_g1hh[128], s_g2hh[128];
  __shared__ __align__(16) h2    s_g1inh[128], s_g2inh[128], s_s2h[128];
  __shared__ __align__(16) h2    s_x1h[128], s_xh[64], s_ctxh[128];
  __shared__ float s_wred[16];

  const int b    = blockIdx.x & 63;
  const int quad = blockIdx.x >> 6;
  const int tid = threadIdx.x;
  const int lane = tid & 63;
  const int wid = tid >> 6;
  const int half_id = lane >> 5;
  const int cl = lane & 31;

  const f16* keyb = keysg + (size_t)b*T*UU;
  const f16* memb = memg  + (size_t)b*T*UU;
  float* outb = out + (size_t)b*80*(steps*RRR);
  const int tq0 = (T*quad)/NQUAD, tq1 = (T*(quad+1))/NQUAD;

  if (tid < 128){
    s_ha[2*tid]=0.f; s_ha[2*tid+1]=0.f;
    s_g1h[2*tid]=0.f; s_g1h[2*tid+1]=0.f;
    s_g2h[2*tid]=0.f; s_g2h[2*tid+1]=0.f;
    h2 z; z[0]=(f16)0.f; z[1]=(f16)0.f;
    s_hah[tid]=z; s_g1hh[tid]=z; s_g2hh[tid]=z;
  }
  if (tid < 80) s_prevf[tid] = (f16)0.f;
  __syncthreads();

  // per-lane v fragments for the score loop: v8 (for Sigma v), m8 = -2v
  float v8[8], m8[8];
  #pragma unroll
  for (int j=0;j<8;j++){ v8[j] = vvec[cl*8+j]; m8[j] = -2.0f*v8[j]; }
  float sumv = 0.f;
  #pragma unroll
  for (int j=0;j<8;j++) sumv += v8[j];
  #pragma unroll
  for (int o=1;o<32;o<<=1) sumv += __shfl_xor(sumv, o);   // Sigma over all 256

  for (int step = 0; step < steps; ++step){
    const int par = step & 1;
    // -- hh GEMVs --
    gemv_stage(wts+O_WAHH, s_hah,  ba_hh, s_gh,  nullptr, s_part, 128, 192, 8, 0, tid);
    gemv_stage(wts+O_W1HH, s_g1hh, b1_hh, s_gh1, nullptr, s_part, 128, 192, 8, 0, tid);
    gemv_stage(wts+O_W2HH, s_g2hh, b2_hh, s_gh2, nullptr, s_part, 128, 192, 8, 0, tid);
    // -- prenet --
    gemv_stage(wts+O_WP1T, reinterpret_cast<const h2*>(s_prevf), bp1, nullptr, s_x1h,
               s_part, 40, 64, 6, 1, tid);
    gemv_stage(wts+O_WP2T, s_x1h, bp2, nullptr, s_xh, s_part, 128, 32, 5, 1, tid);
    // -- attn GRU input + gates --
    gemv_stage(wts+O_WAIH, s_xh, ba_ih, s_gi, nullptr, s_part, 64, 192, 8, 0, tid);
    gru_gate(s_gi, s_gh, s_ha, s_hah, nullptr, nullptr, nullptr, tid);
    // -- q' (prescaled) | g1in(d_t part) --
    gemv_stage(wts+O_WQP, s_hah, wsf+OF_BQP, s_q, nullptr, s_part, 128, 128, 7, 0, tid);

    // -- attention scores on [tq0,tq1): s = sumv + Sigma m_j * rcp(1+2^(k'+q'))
    {
      float q8[8];
      #pragma unroll
      for (int j=0;j<8;j++) q8[j] = s_q[cl*8+j];
      float rs = 0.f;
      for (int t0 = tq0 + wid*2; t0 < tq1; t0 += 32){
        int t = t0 + half_id;
        fv4 kv = *(reinterpret_cast<const fv4*>(keyb + (size_t)t*UU) + cl);
        const h2* kh = reinterpret_cast<const h2*>(&kv);
        float acc = 0.f;
        #pragma unroll
        for (int p=0;p<4;p++){
          float t0f = (float)kh[p][0] + q8[2*p];
          float t1f = (float)kh[p][1] + q8[2*p+1];
          acc = fmaf(m8[2*p],   frcp(1.f + fexp2(t0f)), acc);
          acc = fmaf(m8[2*p+1], frcp(1.f + fexp2(t1f)), acc);
        }
        #pragma unroll
        for (int o=1;o<32;o<<=1) acc += __shfl_xor(acc, o);
        float e = __expf(sumv + acc);
        if (cl == 0) s_sc[t] = e;
        rs += e;
      }
      rs += __shfl_xor(rs, 32);
      if (lane==0) s_wred[wid] = rs;
    }
    __syncthreads();
    // -- ctx partials over [tq0,tq1)
    {
      float c8[8] = {0.f,0.f,0.f,0.f,0.f,0.f,0.f,0.f};
      for (int t0 = tq0 + wid*2; t0 < tq1; t0 += 32){
        int t = t0 + half_id;
        float wgt = s_sc[t];
        fv4 mv = *(reinterpret_cast<const fv4*>(memb + (size_t)t*UU) + cl);
        const h2* mh = reinterpret_cast<const h2*>(&mv);
        #pragma unroll
        for (int p=0;p<4;p++){
          c8[2*p  ] += wgt*(float)mh[p][0];
          c8[2*p+1] += wgt*(float)mh[p][1];
        }
      }
      #pragma unroll
      for (int j=0;j<8;j++) c8[j] += __shfl_xor(c8[j], 32);
      if (half_id == 0){
        float4 lo; lo.x=c8[0]; lo.y=c8[1]; lo.z=c8[2]; lo.w=c8[3];
        float4 hi; hi.x=c8[4]; hi.y=c8[5]; hi.z=c8[6]; hi.w=c8[7];
        *reinterpret_cast<float4*>(s_part + wid*256 + cl*8)     = lo;
        *reinterpret_cast<float4*>(s_part + wid*256 + cl*8 + 4) = hi;
      }
    }
    __syncthreads();
    // -- write this quad's unnormalized partials to device memory
    {
      float* cp = ctxp + (((size_t)b*2 + par)*NQUAD + quad)*256;
      if (tid < 128){
        float a = 0.f, c = 0.f;
        #pragma unroll
        for (int w=0; w<16; ++w){
          a += s_part[w*256 + 2*tid];
          c += s_part[w*256 + 2*tid+1];
        }
        cp[2*tid]   = a;
        cp[2*tid+1] = c;
      }
      if (tid == 0){
        float tot = 0.f;
        #pragma unroll
        for (int w=0; w<16; ++w) tot += s_wred[w];
        esum[((size_t)b*2 + par)*NQUAD + quad] = tot;
      }
    }
    __syncthreads();
    // -- one device-scope sync among the 4 quads of this batch element
    if (tid == 0){
      int* fl = flags + b*256 + step;
      __threadfence();
      __hip_atomic_fetch_add(fl, 1, __ATOMIC_RELEASE, __HIP_MEMORY_SCOPE_AGENT);
      while (__hip_atomic_load(fl, __ATOMIC_ACQUIRE, __HIP_MEMORY_SCOPE_AGENT) < NQUAD){
        __builtin_amdgcn_s_sleep(2);
      }
    }
    __syncthreads();
    // -- combine partials (identical on all quads)
    if (tid < 128){
      const float* cp0 = ctxp + ((size_t)b*2 + par)*NQUAD*256;
      const float* es0 = esum + ((size_t)b*2 + par)*NQUAD;
      float es = 0.f;
      #pragma unroll
      for (int q4=0;q4<NQUAD;q4++)
        es += __hip_atomic_load(&es0[q4], __ATOMIC_RELAXED, __HIP_MEMORY_SCOPE_AGENT);
      float inv = frcp(es);
      float a = 0.f, c = 0.f;
      #pragma unroll
      for (int q4=0;q4<NQUAD;q4++){
        a += __hip_atomic_load(&cp0[q4*256 + 2*tid],   __ATOMIC_RELAXED, __HIP_MEMORY_SCOPE_AGENT);
        c += __hip_atomic_load(&cp0[q4*256 + 2*tid+1], __ATOMIC_RELAXED, __HIP_MEMORY_SCOPE_AGENT);
      }
      h2 p; p[0]=(f16)(a*inv); p[1]=(f16)(c*inv);
      s_ctxh[tid] = p;
    }
    __syncthreads();

    // -- g1in += Wproj_ctx * ctx --
    gemv_stage(wts+O_WPC, s_ctxh, nullptr, s_q+256, s_g1inh, s_part, 128, 64, 6, 2, tid);
    // -- GRU1 --
    gemv_stage(wts+O_W1IH, s_g1inh, b1_ih, s_gi, nullptr, s_part, 128, 192, 8, 0, tid);
    gru_gate(s_gi, s_gh1, s_g1h, s_g1hh, s_q+256, s_g2in, s_g2inh, tid);
    // -- GRU2 --
    gemv_stage(wts+O_W2IH, s_g2inh, b2_ih, s_gi, nullptr, s_part, 128, 192, 8, 0, tid);
    gru_gate(s_gi, s_gh2, s_g2h, s_g2hh, s_g2in, nullptr, s_s2h, tid);
    // -- output projection --
    gemv_stage(wts+O_WOUT, s_s2h, bout, s_y, nullptr, s_part, 128, 100, 7, 0, tid);
    // -- scatter (quad 0 only) + prev update (all quads) --
    if (tid < 400){
      float val = s_y[tid];
      int mel = tid / 5, rr = tid - mel*5;
      if (quad == 0)
        __builtin_nontemporal_store(val, &outb[(size_t)mel*(steps*RRR) + step*RRR + rr]);
      if (rr == 4) s_prevf[mel] = (f16)val;
    }
    __syncthreads();
  }
}

extern "C" void kernel_launch(void* const* d_in, const int* in_sizes, int n_in,
                              void* d_out, int out_size, void* d_ws, size_t ws_size,
                              hipStream_t stream)
{
  const float* mem  = (const float*)d_in[0];
  const float* Wp1  = (const float*)d_in[1];
  const float* bp1  = (const float*)d_in[2];
  const float* Wp2  = (const float*)d_in[3];
  const float* bp2  = (const float*)d_in[4];
  const float* W1   = (const float*)d_in[5];
  const float* W2   = (const float*)d_in[6];
  const float* vv   = (const float*)d_in[7];
  const float* Wa_ih= (const float*)d_in[8];
  const float* Wa_hh= (const float*)d_in[9];
  const float* ba_ih= (const float*)d_in[10];
  const float* ba_hh= (const float*)d_in[11];
  const float* W1_ih= (const float*)d_in[12];
  const float* W1_hh= (const float*)d_in[13];
  const float* b1_ih= (const float*)d_in[14];
  const float* b1_hh= (const float*)d_in[15];
  const float* W2_ih= (const float*)d_in[16];
  const float* W2_hh= (const float*)d_in[17];
  const float* b2_ih= (const float*)d_in[18];
  const float* b2_hh= (const float*)d_in[19];
  const float* Wproj= (const float*)d_in[20];
  const float* bproj= (const float*)d_in[21];
  const float* Wout = (const float*)d_in[22];
  const float* bout = (const float*)d_in[23];

  h2*  wsH2 = (h2*)d_ws;
  f16* wsF16= (f16*)d_ws;
  float* wsF = (float*)d_ws;
  int*  wsI = (int*)d_ws;
  int T = in_sizes[0] / (BB*UU);
  int steps = T / RRR;

  auto tr = [&](const float* src, int srcK, int kbase, size_t off, int N, int K,
                int Ntot, int coloff, float scale){
    int total = N*(K/2);
    k_tr_hx<<<dim3((total+255)/256), dim3(256), 0, stream>>>(
        src, srcK, kbase, wsH2 + off, N, K, Ntot, coloff, scale);
  };
  tr(Wp1,   80,  0, O_WP1T, 256, 80,  256, 0, 1.f);
  tr(Wp2,   256, 0, O_WP2T, 128, 256, 128, 0, 1.f);
  tr(Wa_ih, 128, 0, O_WAIH, 768, 128, 768, 0, 1.f);
  tr(Wa_hh, 256, 0, O_WAHH, 768, 256, 768, 0, 1.f);
  tr(W2,    256, 0, O_WQP,  256, 256, 512, 0, SCL2LOG2E);   // prescale q
  tr(Wproj, 512, 0, O_WQP,  256, 256, 512, 256, 1.f);
  tr(Wproj, 512, 256, O_WPC, 256, 256, 256, 0, 1.f);
  tr(W1_ih, 256, 0, O_W1IH, 768, 256, 768, 0, 1.f);
  tr(W1_hh, 256, 0, O_W1HH, 768, 256, 768, 0, 1.f);
  tr(W2_ih, 256, 0, O_W2IH, 768, 256, 768, 0, 1.f);
  tr(W2_hh, 256, 0, O_W2HH, 768, 256, 768, 0, 1.f);
  tr(Wout,  256, 0, O_WOUT, 400, 256, 400, 0, 1.f);

  k_biasqp<<<dim3(2), dim3(256), 0, stream>>>(bproj, wsF + OF_BQP);
  k_transpose<<<dim3((256*256+255)/256), dim3(256), 0, stream>>>(W1, wsF + OF_W1T, 256, 256);
  k_zero<<<dim3(64), dim3(256), 0, stream>>>(wsI + OI_FLAGS, 64*256);

  int n8 = (BB*T*UU)/8;
  k_memh<<<dim3((n8+255)/256), dim3(256), 0, stream>>>(mem, wsF16 + OH_MEM, n8);
  k_keys<<<dim3((T+127)/128, UU/128, BB), dim3(256), 0, stream>>>(mem, wsF + OF_W1T, wsF16 + OH_KEYS, T);

  k_decode<<<dim3(BB*NQUAD), dim3(1024), 0, stream>>>(wsH2, wsF,
      wsF16 + OH_KEYS, wsF16 + OH_MEM,
      wsF + OF_CTXP, wsF + OF_ESUM, wsI + OI_FLAGS,
      bp1, bp2, vv, ba_ih, ba_hh, b1_ih, b1_hh, b2_ih, b2_hh, bout,
      (float*)d_out, T, steps);
}

// Round 7
// 12428.648 us; speedup vs baseline: 4.7591x; 1.0102x over previous
//
#include <hip/hip_runtime.h>

typedef _Float16 f16;
typedef _Float16 h2 __attribute__((ext_vector_type(2)));
typedef float fv4 __attribute__((ext_vector_type(4)));

#define BB 64
#define UU 256
#define RRR 5
#define NQUAD 4

// ---- h2-unit offsets (weights, pair-interleaved [K/2][N]); h2 = 4 bytes ----
constexpr size_t O_WP1T = 0;        // N=256 K=80
constexpr size_t O_WP2T = 10240;    // N=128 K=256
constexpr size_t O_WAIH = 26624;    // N=768 K=128
constexpr size_t O_WAHH = 75776;    // N=768 K=256
constexpr size_t O_WQP  = 174080;   // N=512 K=256 (W2*2log2e | Wproj[:,0:256])
constexpr size_t O_WPC  = 239616;   // N=256 K=256 (Wproj[:,256:512])
constexpr size_t O_W1IH = 272384;   // N=768 K=256
constexpr size_t O_W1HH = 370688;
constexpr size_t O_W2IH = 468992;
constexpr size_t O_W2HH = 567296;
constexpr size_t O_WOUT = 665600;   // N=400 K=256 -> weights end 716800 h2 = 2,867,200 B
// ---- float-unit offsets ----
constexpr size_t OF_BQP = 716800;   // 512 floats (0|bproj)
constexpr size_t OF_W1T = 717312;   // 65536 floats -> end 782848 f = 3,131,392 B
// ---- half-unit offsets ----
constexpr size_t OH_KEYS = 1565696;             // byte 3,131,392; 64*1000*256 halfs (pre-scaled)
constexpr size_t OH_MEM  = OH_KEYS + 16384000;  // byte 35,899,392 -> end byte 68,667,392
// ---- cross-block exchange (float/int units) ----
constexpr size_t OF_CTXP  = 17166848;  // ctx_part [64][2][4][256] floats
constexpr size_t OF_ESUM  = 17297920;  // esum     [64][2][4] floats
constexpr size_t OI_FLAGS = 17298432;  // flags    [64][256] ints

#define SCL2LOG2E 2.8853900817779268f

#if defined(__has_builtin)
#if __has_builtin(__builtin_amdgcn_fdot2)
#define USE_FDOT2 1
#endif
#endif

__device__ __forceinline__ float dot2f(h2 a, h2 b, float c){
#ifdef USE_FDOT2
  return __builtin_amdgcn_fdot2(a, b, c, false);
#else
  return c + (float)a[0]*(float)b[0] + (float)a[1]*(float)b[1];
#endif
}

__device__ __forceinline__ float frcp(float x){ return __builtin_amdgcn_rcpf(x); }
__device__ __forceinline__ float fexp2(float x){ return __builtin_amdgcn_exp2f(x); }
__device__ __forceinline__ float fsig(float x){ return frcp(1.0f + fexp2(-1.4426950408889634f*x)); }
__device__ __forceinline__ float ftanh(float x){ return 1.0f - 2.0f*frcp(1.0f + fexp2(SCL2LOG2E*x)); }

// ---------------- setup kernels ----------------
__global__ void k_tr_hx(const float* __restrict__ src, int srcK, int kbase,
                        h2* __restrict__ dst, int N, int K, int Ntot, int coloff,
                        float scale){
  int idx = blockIdx.x*blockDim.x + threadIdx.x;
  int tot = N*(K/2);
  if (idx < tot){
    int k2 = idx / N, n = idx - k2*N;
    h2 p; p[0]=(f16)(scale*src[n*srcK + kbase + 2*k2]);
    p[1]=(f16)(scale*src[n*srcK + kbase + 2*k2+1]);
    dst[(size_t)k2*Ntot + coloff + n] = p;
  }
}

__global__ void k_transpose(const float* __restrict__ src, float* __restrict__ dst, int N, int K){
  int idx = blockIdx.x*blockDim.x + threadIdx.x;
  if (idx < N*K){
    int n = idx / K, k = idx - n*K;
    dst[k*N + n] = src[idx];
  }
}

__global__ void k_biasqp(const float* __restrict__ bproj, float* __restrict__ dst){
  int i = blockIdx.x*blockDim.x + threadIdx.x;
  if (i < 512) dst[i] = (i < 256) ? 0.f : bproj[i-256];
}

__global__ void k_zero(int* __restrict__ p, int n){
  int i = blockIdx.x*blockDim.x + threadIdx.x;
  if (i < n) p[i] = 0;
}

__global__ void k_memh(const float* __restrict__ src, f16* __restrict__ dst, int n8){
  int i = blockIdx.x*blockDim.x + threadIdx.x;
  if (i < n8){
    const float4* s = reinterpret_cast<const float4*>(src) + 2*(size_t)i;
    float4 f0 = s[0], f1 = s[1];
    union { f16 h[8]; float4 v; } u;
    u.h[0]=(f16)f0.x; u.h[1]=(f16)f0.y; u.h[2]=(f16)f0.z; u.h[3]=(f16)f0.w;
    u.h[4]=(f16)f1.x; u.h[5]=(f16)f1.y; u.h[6]=(f16)f1.z; u.h[7]=(f16)f1.w;
    reinterpret_cast<float4*>(dst)[i] = u.v;
  }
}

// keys[b][t][c] = 2log2e * sum_u mem[b][t][u]*W1[c][u]; fp16 out
__global__ __launch_bounds__(256) void k_keys(const float* __restrict__ mem,
      const float* __restrict__ W1t, f16* __restrict__ keys, int T)
{
  const int b = blockIdx.z;
  const int tbase = blockIdx.x * 128;
  const int cbase = blockIdx.y * 128;
  const int tid = threadIdx.x;
  const int rt = tid >> 4, ct = tid & 15;
  const float* memb = mem + (size_t)b*T*UU;

  float acc[8][8];
  #pragma unroll
  for (int i=0;i<8;i++){
    #pragma unroll
    for (int j=0;j<8;j++) acc[i][j]=0.f;
  }
  const float* arow[8];
  #pragma unroll
  for (int i=0;i<8;i++){
    int t = tbase + rt*8 + i;
    arow[i] = memb + (size_t)(t < T ? t : T-1)*UU;
  }
  const float* wcol = W1t + cbase + ct*8;

  for (int k=0;k<UU;k+=4){
    float w8[4][8];
    #pragma unroll
    for (int kk=0;kk<4;kk++){
      float4 lo = *reinterpret_cast<const float4*>(wcol + (size_t)(k+kk)*UU);
      float4 hi = *reinterpret_cast<const float4*>(wcol + (size_t)(k+kk)*UU + 4);
      w8[kk][0]=lo.x; w8[kk][1]=lo.y; w8[kk][2]=lo.z; w8[kk][3]=lo.w;
      w8[kk][4]=hi.x; w8[kk][5]=hi.y; w8[kk][6]=hi.z; w8[kk][7]=hi.w;
    }
    #pragma unroll
    for (int i=0;i<8;i++){
      float4 a = *reinterpret_cast<const float4*>(arow[i] + k);
      float a4[4] = {a.x, a.y, a.z, a.w};
      #pragma unroll
      for (int kk=0;kk<4;kk++){
        #pragma unroll
        for (int j=0;j<8;j++) acc[i][j] += a4[kk]*w8[kk][j];
      }
    }
  }
  #pragma unroll
  for (int i=0;i<8;i++){
    int t = tbase + rt*8 + i;
    if (t < T){
      f16* dst = keys + (size_t)b*T*UU + (size_t)t*UU + cbase + ct*8;
      union { f16 h[8]; float4 v; } u;
      #pragma unroll
      for (int j=0;j<8;j++) u.h[j] = (f16)(acc[i][j]*SCL2LOG2E);
      *reinterpret_cast<float4*>(dst) = u.v;
    }
  }
}

// ---------------- shfl-combined GEMV (one barrier-phase, no LDS partials) ----------------
// 2-way K-split: lanes l and l^32 of a wave compute the two K-halves of the
// same output column; combine via shfl_xor(32). Caller passes local = tid - base
// where base is a multiple of 64. Thread count per call = ceil(Nf4/32)*64.
// act: 0 = +bias, 1 = relu(+bias), 2 = accumulate into destf (no bias).
__device__ __attribute__((noinline)) void gemv_shfl(
    const h2* __restrict__ W, const h2* __restrict__ in,
    const float* __restrict__ bias, float* __restrict__ destf, h2* __restrict__ desth,
    int K2, int Nf4, int act, int local)
{
  const int lane = local & 63;
  const int half = lane >> 5;
  int col = (local >> 6)*32 + (lane & 31);
  const bool valid = col < Nf4;
  if (!valid) col = 0;
  const int kh = K2 >> 1;
  const float4* w = reinterpret_cast<const float4*>(W) + (size_t)(half*kh)*Nf4 + col;
  const h2* ia = in + half*kh;
  float a0=0.f, a1=0.f, a2=0.f, a3=0.f;
  #pragma unroll 8
  for (int it = 0; it < kh; ++it){
    float4 wp = w[(size_t)it*Nf4];
    h2 a = ia[it];
    const h2* wh = reinterpret_cast<const h2*>(&wp);
    a0 = dot2f(wh[0], a, a0);
    a1 = dot2f(wh[1], a, a1);
    a2 = dot2f(wh[2], a, a2);
    a3 = dot2f(wh[3], a, a3);
  }
  a0 += __shfl_xor(a0, 32, 64);
  a1 += __shfl_xor(a1, 32, 64);
  a2 += __shfl_xor(a2, 32, 64);
  a3 += __shfl_xor(a3, 32, 64);
  if (half == 0 && valid){
    if (bias){
      const float4 bv = reinterpret_cast<const float4*>(bias)[col];
      a0+=bv.x; a1+=bv.y; a2+=bv.z; a3+=bv.w;
    }
    if (act == 1){
      a0=fmaxf(a0,0.f); a1=fmaxf(a1,0.f); a2=fmaxf(a2,0.f); a3=fmaxf(a3,0.f);
    } else if (act == 2){
      const float4 d = reinterpret_cast<float4*>(destf)[col];
      a0+=d.x; a1+=d.y; a2+=d.z; a3+=d.w;
    }
    if (destf){
      float4 r; r.x=a0; r.y=a1; r.z=a2; r.w=a3;
      reinterpret_cast<float4*>(destf)[col] = r;
    }
    if (desth){
      h2 p0; p0[0]=(f16)a0; p0[1]=(f16)a1;
      h2 p1; p1[0]=(f16)a2; p1[1]=(f16)a3;
      desth[2*col] = p0; desth[2*col+1] = p1;
    }
  }
}

__device__ __attribute__((noinline)) void gru_gate(
    const float* __restrict__ gi, const float* __restrict__ gh,
    float* __restrict__ h, h2* __restrict__ hh2,
    const float* __restrict__ addsrc, float* __restrict__ sumf,
    h2* __restrict__ sumh, int tid)
{
  if (tid < 128){
    float hn[2], sm[2] = {0.f, 0.f};
    #pragma unroll
    for (int d=0; d<2; ++d){
      int e = 2*tid + d;
      float r = fsig(gi[e] + gh[e]);
      float z = fsig(gi[256+e] + gh[256+e]);
      float n = ftanh(gi[512+e] + r*gh[512+e]);
      hn[d] = (1.f - z)*n + z*h[e];
      h[e] = hn[d];
      if (addsrc){ sm[d] = addsrc[e] + hn[d]; if (sumf) sumf[e] = sm[d]; }
    }
    h2 p; p[0]=(f16)hn[0]; p[1]=(f16)hn[1];
    hh2[tid] = p;
    if (addsrc && sumh){ h2 q; q[0]=(f16)sm[0]; q[1]=(f16)sm[1]; sumh[tid] = q; }
  }
  __syncthreads();
}

// ---------------- persistent decoder: 4 blocks per batch element ----------------
__global__ __launch_bounds__(1024) void k_decode(
    const h2* __restrict__ wts, const float* __restrict__ wsf,
    const f16* __restrict__ keysg, const f16* __restrict__ memg,
    float* __restrict__ ctxp, float* __restrict__ esum, int* __restrict__ flags,
    const float* __restrict__ bp1, const float* __restrict__ bp2,
    const float* __restrict__ vvec,
    const float* __restrict__ ba_ih, const float* __restrict__ ba_hh,
    const float* __restrict__ b1_ih, const float* __restrict__ b1_hh,
    const float* __restrict__ b2_ih, const float* __restrict__ b2_hh,
    const float* __restrict__ bout,
    float* __restrict__ out, int T, int steps)
{
  __shared__ __align__(16) float s_red[4096];    // ctx partials (16 waves x 256)
  __shared__ __align__(16) float s_sc[1024];
  __shared__ __align__(16) float s_gi[768];
  __shared__ __align__(16) float s_gh[768];
  __shared__ __align__(16) float s_gh1[768];
  __shared__ __align__(16) float s_gh2[768];
  __shared__ __align__(16) float s_q[512];       // [0:256]=q', [256:512]=g1in
  __shared__ __align__(16) float s_ha[256];
  __shared__ __align__(16) float s_g1h[256];
  __shared__ __align__(16) float s_g2h[256];
  __shared__ __align__(16) float s_g2in[256];
  __shared__ __align__(16) float s_y[400];
  __shared__ __align__(16) f16   s_prevf[80];
  __shared__ __align__(16) h2    s_hah[128], s_g1hh[128], s_g2hh[128];
  __shared__ __align__(16) h2    s_g1inh[128], s_g2inh[128], s_s2h[128];
  __shared__ __align__(16) h2    s_x1h[128], s_xh[64], s_ctxh[128];
  __shared__ float s_wred[16];

  const int b    = blockIdx.x & 63;
  const int quad = blockIdx.x >> 6;
  const int tid = threadIdx.x;
  const int lane = tid & 63;
  const int wid = tid >> 6;
  const int half_id = lane >> 5;
  const int cl = lane & 31;

  const f16* keyb = keysg + (size_t)b*T*UU;
  const f16* memb = memg  + (size_t)b*T*UU;
  float* outb = out + (size_t)b*80*(steps*RRR);
  const int tq0 = (T*quad)/NQUAD, tq1 = (T*(quad+1))/NQUAD;

  if (tid < 128){
    s_ha[2*tid]=0.f; s_ha[2*tid+1]=0.f;
    s_g1h[2*tid]=0.f; s_g1h[2*tid+1]=0.f;
    s_g2h[2*tid]=0.f; s_g2h[2*tid+1]=0.f;
    h2 z; z[0]=(f16)0.f; z[1]=(f16)0.f;
    s_hah[tid]=z; s_g1hh[tid]=z; s_g2hh[tid]=z;
  }
  if (tid < 80) s_prevf[tid] = (f16)0.f;
  __syncthreads();

  float v8[8], m8[8];
  #pragma unroll
  for (int j=0;j<8;j++){ v8[j] = vvec[cl*8+j]; m8[j] = -2.0f*v8[j]; }
  float sumv = 0.f;
  #pragma unroll
  for (int j=0;j<8;j++) sumv += v8[j];
  #pragma unroll
  for (int o=1;o<32;o<<=1) sumv += __shfl_xor(sumv, o);

  for (int step = 0; step < steps; ++step){
    const int par = step & 1;
    // L1: WAHH || W1HH || prenet1
    if (tid < 384)      gemv_shfl(wts+O_WAHH, s_hah,  ba_hh, s_gh,  nullptr, 128, 192, 0, tid);
    else if (tid < 768) gemv_shfl(wts+O_W1HH, s_g1hh, b1_hh, s_gh1, nullptr, 128, 192, 0, tid-384);
    else if (tid < 896) gemv_shfl(wts+O_WP1T, reinterpret_cast<const h2*>(s_prevf), bp1,
                                  nullptr, s_x1h, 40, 64, 1, tid-768);
    __syncthreads();
    // L2: W2HH || prenet2
    if (tid < 384)      gemv_shfl(wts+O_W2HH, s_g2hh, b2_hh, s_gh2, nullptr, 128, 192, 0, tid);
    else if (tid < 448) gemv_shfl(wts+O_WP2T, s_x1h, bp2, nullptr, s_xh, 128, 32, 1, tid-384);
    __syncthreads();
    // L3: WAIH
    if (tid < 384) gemv_shfl(wts+O_WAIH, s_xh, ba_ih, s_gi, nullptr, 64, 192, 0, tid);
    __syncthreads();
    // gate_a -> d_t
    gru_gate(s_gi, s_gh, s_ha, s_hah, nullptr, nullptr, nullptr, tid);
    // L5: q' | g1in
    if (tid < 256) gemv_shfl(wts+O_WQP, s_hah, wsf+OF_BQP, s_q, nullptr, 128, 128, 0, tid);
    __syncthreads();

    // attention scores on [tq0,tq1)
    {
      float q8[8];
      #pragma unroll
      for (int j=0;j<8;j++) q8[j] = s_q[cl*8+j];
      float rs = 0.f;
      for (int t0 = tq0 + wid*2; t0 < tq1; t0 += 32){
        int t = t0 + half_id;
        fv4 kv = *(reinterpret_cast<const fv4*>(keyb + (size_t)t*UU) + cl);
        const h2* kh = reinterpret_cast<const h2*>(&kv);
        float acc = 0.f;
        #pragma unroll
        for (int p=0;p<4;p++){
          float t0f = (float)kh[p][0] + q8[2*p];
          float t1f = (float)kh[p][1] + q8[2*p+1];
          acc = fmaf(m8[2*p],   frcp(1.f + fexp2(t0f)), acc);
          acc = fmaf(m8[2*p+1], frcp(1.f + fexp2(t1f)), acc);
        }
        #pragma unroll
        for (int o=1;o<32;o<<=1) acc += __shfl_xor(acc, o);
        float e = __expf(sumv + acc);
        if (cl == 0) s_sc[t] = e;
        rs += e;
      }
      rs += __shfl_xor(rs, 32);
      if (lane==0) s_wred[wid] = rs;
    }
    __syncthreads();
    // ctx partials over [tq0,tq1)
    {
      float c8[8] = {0.f,0.f,0.f,0.f,0.f,0.f,0.f,0.f};
      for (int t0 = tq0 + wid*2; t0 < tq1; t0 += 32){
        int t = t0 + half_id;
        float wgt = s_sc[t];
        fv4 mv = *(reinterpret_cast<const fv4*>(memb + (size_t)t*UU) + cl);
        const h2* mh = reinterpret_cast<const h2*>(&mv);
        #pragma unroll
        for (int p=0;p<4;p++){
          c8[2*p  ] += wgt*(float)mh[p][0];
          c8[2*p+1] += wgt*(float)mh[p][1];
        }
      }
      #pragma unroll
      for (int j=0;j<8;j++) c8[j] += __shfl_xor(c8[j], 32);
      if (half_id == 0){
        float4 lo; lo.x=c8[0]; lo.y=c8[1]; lo.z=c8[2]; lo.w=c8[3];
        float4 hi; hi.x=c8[4]; hi.y=c8[5]; hi.z=c8[6]; hi.w=c8[7];
        *reinterpret_cast<float4*>(s_red + wid*256 + cl*8)     = lo;
        *reinterpret_cast<float4*>(s_red + wid*256 + cl*8 + 4) = hi;
      }
    }
    __syncthreads();
    // write this quad's unnormalized partials
    {
      float* cp = ctxp + (((size_t)b*2 + par)*NQUAD + quad)*256;
      if (tid < 128){
        float a = 0.f, c = 0.f;
        #pragma unroll
        for (int w=0; w<16; ++w){
          a += s_red[w*256 + 2*tid];
          c += s_red[w*256 + 2*tid+1];
        }
        cp[2*tid]   = a;
        cp[2*tid+1] = c;
      }
      if (tid == 0){
        float tot = 0.f;
        #pragma unroll
        for (int w=0; w<16; ++w) tot += s_wred[w];
        esum[((size_t)b*2 + par)*NQUAD + quad] = tot;
      }
    }
    __syncthreads();
    // device-scope sync among the 4 quads of this batch element
    if (tid == 0){
      int* fl = flags + b*256 + step;
      __threadfence();
      __hip_atomic_fetch_add(fl, 1, __ATOMIC_RELEASE, __HIP_MEMORY_SCOPE_AGENT);
      while (__hip_atomic_load(fl, __ATOMIC_ACQUIRE, __HIP_MEMORY_SCOPE_AGENT) < NQUAD){
        __builtin_amdgcn_s_sleep(2);
      }
    }
    __syncthreads();
    // combine partials (identical on all quads)
    if (tid < 128){
      const float* cp0 = ctxp + ((size_t)b*2 + par)*NQUAD*256;
      const float* es0 = esum + ((size_t)b*2 + par)*NQUAD;
      float es = 0.f;
      #pragma unroll
      for (int q4=0;q4<NQUAD;q4++)
        es += __hip_atomic_load(&es0[q4], __ATOMIC_RELAXED, __HIP_MEMORY_SCOPE_AGENT);
      float inv = frcp(es);
      float a = 0.f, c = 0.f;
      #pragma unroll
      for (int q4=0;q4<NQUAD;q4++){
        a += __hip_atomic_load(&cp0[q4*256 + 2*tid],   __ATOMIC_RELAXED, __HIP_MEMORY_SCOPE_AGENT);
        c += __hip_atomic_load(&cp0[q4*256 + 2*tid+1], __ATOMIC_RELAXED, __HIP_MEMORY_SCOPE_AGENT);
      }
      h2 p; p[0]=(f16)(a*inv); p[1]=(f16)(c*inv);
      s_ctxh[tid] = p;
    }
    __syncthreads();

    // WPC: g1in += Wproj_ctx * ctx
    if (tid < 128) gemv_shfl(wts+O_WPC, s_ctxh, nullptr, s_q+256, s_g1inh, 128, 64, 2, tid);
    __syncthreads();
    // W1IH
    if (tid < 384) gemv_shfl(wts+O_W1IH, s_g1inh, b1_ih, s_gi, nullptr, 128, 192, 0, tid);
    __syncthreads();
    gru_gate(s_gi, s_gh1, s_g1h, s_g1hh, s_q+256, s_g2in, s_g2inh, tid);
    // W2IH
    if (tid < 384) gemv_shfl(wts+O_W2IH, s_g2inh, b2_ih, s_gi, nullptr, 128, 192, 0, tid);
    __syncthreads();
    gru_gate(s_gi, s_gh2, s_g2h, s_g2hh, s_g2in, nullptr, s_s2h, tid);
    // WOUT
    if (tid < 256) gemv_shfl(wts+O_WOUT, s_s2h, bout, s_y, nullptr, 128, 100, 0, tid);
    __syncthreads();
    // scatter (quad 0 only) + prev update
    if (tid < 400){
      float val = s_y[tid];
      int mel = tid / 5, rr = tid - mel*5;
      if (quad == 0)
        __builtin_nontemporal_store(val, &outb[(size_t)mel*(steps*RRR) + step*RRR + rr]);
      if (rr == 4) s_prevf[mel] = (f16)val;
    }
    __syncthreads();
  }
}

extern "C" void kernel_launch(void* const* d_in, const int* in_sizes, int n_in,
                              void* d_out, int out_size, void* d_ws, size_t ws_size,
                              hipStream_t stream)
{
  const float* mem  = (const float*)d_in[0];
  const float* Wp1  = (const float*)d_in[1];
  const float* bp1  = (const float*)d_in[2];
  const float* Wp2  = (const float*)d_in[3];
  const float* bp2  = (const float*)d_in[4];
  const float* W1   = (const float*)d_in[5];
  const float* W2   = (const float*)d_in[6];
  const float* vv   = (const float*)d_in[7];
  const float* Wa_ih= (const float*)d_in[8];
  const float* Wa_hh= (const float*)d_in[9];
  const float* ba_ih= (const float*)d_in[10];
  const float* ba_hh= (const float*)d_in[11];
  const float* W1_ih= (const float*)d_in[12];
  const float* W1_hh= (const float*)d_in[13];
  const float* b1_ih= (const float*)d_in[14];
  const float* b1_hh= (const float*)d_in[15];
  const float* W2_ih= (const float*)d_in[16];
  const float* W2_hh= (const float*)d_in[17];
  const float* b2_ih= (const float*)d_in[18];
  const float* b2_hh= (const float*)d_in[19];
  const float* Wproj= (const float*)d_in[20];
  const float* bproj= (const float*)d_in[21];
  const float* Wout = (const float*)d_in[22];
  const float* bout = (const float*)d_in[23];

  h2*  wsH2 = (h2*)d_ws;
  f16* wsF16= (f16*)d_ws;
  float* wsF = (float*)d_ws;
  int*  wsI = (int*)d_ws;
  int T = in_sizes[0] / (BB*UU);
  int steps = T / RRR;

  auto tr = [&](const float* src, int srcK, int kbase, size_t off, int N, int K,
                int Ntot, int coloff, float scale){
    int total = N*(K/2);
    k_tr_hx<<<dim3((total+255)/256), dim3(256), 0, stream>>>(
        src, srcK, kbase, wsH2 + off, N, K, Ntot, coloff, scale);
  };
  tr(Wp1,   80,  0, O_WP1T, 256, 80,  256, 0, 1.f);
  tr(Wp2,   256, 0, O_WP2T, 128, 256, 128, 0, 1.f);
  tr(Wa_ih, 128, 0, O_WAIH, 768, 128, 768, 0, 1.f);
  tr(Wa_hh, 256, 0, O_WAHH, 768, 256, 768, 0, 1.f);
  tr(W2,    256, 0, O_WQP,  256, 256, 512, 0, SCL2LOG2E);
  tr(Wproj, 512, 0, O_WQP,  256, 256, 512, 256, 1.f);
  tr(Wproj, 512, 256, O_WPC, 256, 256, 256, 0, 1.f);
  tr(W1_ih, 256, 0, O_W1IH, 768, 256, 768, 0, 1.f);
  tr(W1_hh, 256, 0, O_W1HH, 768, 256, 768, 0, 1.f);
  tr(W2_ih, 256, 0, O_W2IH, 768, 256, 768, 0, 1.f);
  tr(W2_hh, 256, 0, O_W2HH, 768, 256, 768, 0, 1.f);
  tr(Wout,  256, 0, O_WOUT, 400, 256, 400, 0, 1.f);

  k_biasqp<<<dim3(2), dim3(256), 0, stream>>>(bproj, wsF + OF_BQP);
  k_transpose<<<dim3((256*256+255)/256), dim3(256), 0, stream>>>(W1, wsF + OF_W1T, 256, 256);
  k_zero<<<dim3(64), dim3(256), 0, stream>>>(wsI + OI_FLAGS, 64*256);

  int n8 = (BB*T*UU)/8;
  k_memh<<<dim3((n8+255)/256), dim3(256), 0, stream>>>(mem, wsF16 + OH_MEM, n8);
  k_keys<<<dim3((T+127)/128, UU/128, BB), dim3(256), 0, stream>>>(mem, wsF + OF_W1T, wsF16 + OH_KEYS, T);

  k_decode<<<dim3(BB*NQUAD), dim3(1024), 0, stream>>>(wsH2, wsF,
      wsF16 + OH_KEYS, wsF16 + OH_MEM,
      wsF + OF_CTXP, wsF + OF_ESUM, wsI + OI_FLAGS,
      bp1, bp2, vv, ba_ih, ba_hh, b1_ih, b1_hh, b2_ih, b2_hh, bout,
      (float*)d_out, T, steps);
}